// Round 13
// baseline (216.649 us; speedup 1.0000x reference)
//
#include <hip/hip_runtime.h>
#include <hip/hip_bf16.h>
#include <math.h>

// Problem: B=1, N=1024, D=1024, H=16, C=64, TOPK=2, HD=64, G=16
// Inputs (float32): x, Wq, Wk, Wv [1024x1024], Wg[32,1024], Wo[1024,1024]
// Output (float32): [1024,1024]
//
// Selection is computed EXACTLY in f32 without Q:
//   kc = (chunk-mean x) @ Wk^T          (exact, linear)
//   U[h,g][f] = sum_d kc[g][h*64+d] * Wq[h*64+d][f]
//   score(n,h,g) = x_n . U[h,g]         (f32 VALU GEMM)
// => Q/K/V projections are plain bf16 MFMA (1 unit each), K/V epilogues emit
// packed bf16 pairs directly. Wo GEMM: oh (bf16) x (Woh + Wol) = 2 units.
// Attention: one wave per (n,h), dot2 bf16 pairs, readlane broadcasts.

typedef __attribute__((ext_vector_type(8))) short short8;   // 8 bf16 = 4 VGPRs
typedef __attribute__((ext_vector_type(4))) float f32x4;
typedef __attribute__((ext_vector_type(2))) __bf16 bf16x2v;

#define NTOK 1024
#define DMODEL 1024
#define NHEAD 16
#define HDIM 64
#define CHUNK 64
#define NBLK 16

__device__ __forceinline__ unsigned rlu(unsigned v, int l)
{
    return (unsigned)__builtin_amdgcn_readlane((int)v, l);
}

__device__ __forceinline__ unsigned short bf16bits(float v)
{
    __hip_bfloat16 h = __float2bfloat16(v);
    return __builtin_bit_cast(unsigned short, h);
}

// acc += a.lo*b.lo + a.hi*b.hi  (bf16 pairs packed in uints)
__device__ __forceinline__ float dot2bf(unsigned a, unsigned b, float acc)
{
#if __has_builtin(__builtin_amdgcn_fdot2_f32_bf16)
    return __builtin_amdgcn_fdot2_f32_bf16(
        __builtin_bit_cast(bf16x2v, a), __builtin_bit_cast(bf16x2v, b), acc, false);
#else
    float a0 = __uint_as_float(a << 16), a1 = __uint_as_float(a & 0xffff0000u);
    float b0 = __uint_as_float(b << 16), b1 = __uint_as_float(b & 0xffff0000u);
    return acc + a0 * b0 + a1 * b1;
#endif
}

// pack (own, lane^1) bf16 bits into a uint; valid at EVEN lanes (own=low)
__device__ __forceinline__ unsigned packpair(float v)
{
    unsigned b = bf16bits(v);
    unsigned nb = (unsigned)__shfl_xor((int)b, 1) & 0xffffu;
    return b | (nb << 16);
}

// ---------------------------------------------------------------------------
// Merged pre-cast. which = blockIdx.x>>10:
// 0: x hi  1: Wq hi  2: Wk hi  3: Wv hi  4: Wo split (hi+lo)
// ---------------------------------------------------------------------------
__global__ __launch_bounds__(256) void cast_all_kernel(
    const float* __restrict__ x,  const float* __restrict__ Wq,
    const float* __restrict__ Wk, const float* __restrict__ Wv,
    const float* __restrict__ Wo,
    __hip_bfloat16* __restrict__ xh,  __hip_bfloat16* __restrict__ Wqh,
    __hip_bfloat16* __restrict__ Wkh, __hip_bfloat16* __restrict__ Wvh,
    __hip_bfloat16* __restrict__ Woh, __hip_bfloat16* __restrict__ Wol)
{
    const int which = blockIdx.x >> 10;
    const int b = blockIdx.x & 1023;
    const int i = (b * 256 + threadIdx.x) * 4;
    const float* in; __hip_bfloat16 *hi, *lo = nullptr;
    if (which == 0)      { in = x;  hi = xh;  }
    else if (which == 1) { in = Wq; hi = Wqh; }
    else if (which == 2) { in = Wk; hi = Wkh; }
    else if (which == 3) { in = Wv; hi = Wvh; }
    else                 { in = Wo; hi = Woh; lo = Wol; }

    float4 v = *(const float4*)(in + i);
    float vv[4] = {v.x, v.y, v.z, v.w};
    __hip_bfloat16 h[4], l[4];
    #pragma unroll
    for (int j = 0; j < 4; j++) {
        h[j] = __float2bfloat16(vv[j]);
        l[j] = __float2bfloat16(vv[j] - __bfloat162float(h[j]));
    }
    *(uint2*)(hi + i) = *(uint2*)h;
    if (lo) *(uint2*)(lo + i) = *(uint2*)l;
}

// ---------------------------------------------------------------------------
// xm[g][f] = mean over c of x[g*64+c][f]  (exact f32). grid 64 = 16g x 4fc.
// ---------------------------------------------------------------------------
__global__ __launch_bounds__(256) void xm_kernel(
    const float* __restrict__ x, float* __restrict__ xm)
{
    const int g = blockIdx.x >> 2;
    const int f = (blockIdx.x & 3) * 256 + threadIdx.x;
    float s = 0.f;
    #pragma unroll 8
    for (int c = 0; c < CHUNK; c++) s += x[(size_t)(g * CHUNK + c) * DMODEL + f];
    xm[g * DMODEL + f] = s * (1.0f / CHUNK);
}

// ---------------------------------------------------------------------------
// kc = xm @ Wk^T  (exact f32). One block per f; (g = tid>>4, sub = tid&15).
// ---------------------------------------------------------------------------
__global__ __launch_bounds__(256) void kc_gemm_kernel(
    const float* __restrict__ xm, const float* __restrict__ Wk,
    float* __restrict__ kc)
{
    const int f = blockIdx.x;
    const int g = threadIdx.x >> 4;
    const int sub = threadIdx.x & 15;
    const float* wrow = Wk + (size_t)f * DMODEL;
    float s = 0.f;
    #pragma unroll 16
    for (int i = 0; i < 64; i++) {
        int e = i * 16 + sub;
        s += xm[g * DMODEL + e] * wrow[e];
    }
    #pragma unroll
    for (int off = 8; off; off >>= 1) s += __shfl_xor(s, off);
    if (sub == 0) kc[g * DMODEL + f] = s;
}

// ---------------------------------------------------------------------------
// Ut[f][(h<<4)|g] = sum_d kc[g][h*64+d] * Wq[h*64+d][f]   (exact f32)
// One block per (h,g); threads stride over f (coalesced on Wq rows).
// ---------------------------------------------------------------------------
__global__ __launch_bounds__(256) void u_kernel(
    const float* __restrict__ kc, const float* __restrict__ Wq,
    float* __restrict__ Ut)
{
    __shared__ float kcs[64];
    const int h = blockIdx.x >> 4, g = blockIdx.x & 15;
    if (threadIdx.x < 64) kcs[threadIdx.x] = kc[g * DMODEL + h * HDIM + threadIdx.x];
    __syncthreads();
    const int col = (h << 4) | g;
    for (int f = threadIdx.x; f < DMODEL; f += 256) {
        float s = 0.f;
        #pragma unroll 16
        for (int d = 0; d < 64; d++)
            s += kcs[d] * Wq[(size_t)(h * HDIM + d) * DMODEL + f];
        Ut[(size_t)f * 256 + col] = s;
    }
}

// ---------------------------------------------------------------------------
// score + top-2, EXACT f32: score(n, h, g) = x_n . Ut[:, (h,g)].
// One block per 4 tokens; thread t = (h<<4)|g accumulates 4 scores.
// Then 64 threads do the masked top-2 scan (ties -> lowest index; all-masked
// -> (0,1), matching jax.lax.top_k).
// ---------------------------------------------------------------------------
__global__ __launch_bounds__(256) void score_top2_kernel(
    const float* __restrict__ x, const float* __restrict__ Ut,
    int2* __restrict__ idx_t)
{
    __shared__ float Xs[4][1024];      // 16 KB
    __shared__ float sc[4][256];       // 4 KB
    const int n0 = blockIdx.x * 4;
    for (int i = threadIdx.x; i < 4 * 1024; i += 256) {
        int j = i >> 10, f = i & 1023;
        Xs[j][f] = x[(size_t)(n0 + j) * DMODEL + f];
    }
    __syncthreads();
    const int t = threadIdx.x;
    float a0 = 0.f, a1 = 0.f, a2 = 0.f, a3 = 0.f;
    #pragma unroll 8
    for (int f = 0; f < DMODEL; f++) {
        float u = Ut[(size_t)f * 256 + t];
        a0 += Xs[0][f] * u;
        a1 += Xs[1][f] * u;
        a2 += Xs[2][f] * u;
        a3 += Xs[3][f] * u;
    }
    sc[0][t] = a0; sc[1][t] = a1; sc[2][t] = a2; sc[3][t] = a3;
    __syncthreads();
    if (t < 64) {
        const int j = t >> 4, h = t & 15;
        const int n = n0 + j;
        float s[NBLK];
        #pragma unroll
        for (int g = 0; g < NBLK; g++)
            s[g] = (n >= (g << 6)) ? -INFINITY : sc[j][h * 16 + g];
        int i1 = -1; float b1 = -INFINITY;
        #pragma unroll
        for (int g = 0; g < NBLK; g++) if (i1 < 0 || s[g] > b1) { b1 = s[g]; i1 = g; }
        int i2 = -1; float b2 = -INFINITY;
        #pragma unroll
        for (int g = 0; g < NBLK; g++) { if (g == i1) continue; if (i2 < 0 || s[g] > b2) { b2 = s[g]; i2 = g; } }
        idx_t[(h << 10) | n] = make_int2(i1, i2);
    }
}

// ---------------------------------------------------------------------------
// QKV GEMM, 64x64 tile, plain bf16 (4 MFMA/iter). widx = blockIdx.x>>4:
//  0: Q -> f32 store.  1: K -> Ktp packed transposed.  2: V -> Vp row-pairs.
// ---------------------------------------------------------------------------
__global__ __launch_bounds__(256) void gemm_qkv(
    const __hip_bfloat16* __restrict__ xh,
    const __hip_bfloat16* __restrict__ Wqh, const __hip_bfloat16* __restrict__ Wkh,
    const __hip_bfloat16* __restrict__ Wvh,
    float* __restrict__ Q, unsigned* __restrict__ Ktp, unsigned* __restrict__ Vp)
{
    __shared__ alignas(16) __hip_bfloat16 Ash[64][40];
    __shared__ alignas(16) __hip_bfloat16 Bsh[64][40];

    const int widx = blockIdx.x >> 4;
    const __hip_bfloat16* __restrict__ Bh =
        (widx == 0) ? Wqh : (widx == 1) ? Wkh : Wvh;
    const int n0 = (blockIdx.x & 15) * 64;
    const int m0 = blockIdx.y * 64;

    const int tid  = threadIdx.x;
    const int wave = tid >> 6;
    const int lane = tid & 63;
    const int lr = tid >> 2;
    const int lc = (tid & 3) * 8;
    const int wm = (wave >> 1) * 32;
    const int wn = (wave & 1) * 32;
    const int fr = lane & 15;
    const int quad = lane >> 4;

    f32x4 acc[2][2] = {};

    for (int k0 = 0; k0 < DMODEL; k0 += 32) {
        const size_t aoff = (size_t)(m0 + lr) * DMODEL + k0 + lc;
        const size_t boff = (size_t)(n0 + lr) * DMODEL + k0 + lc;
        *(uint4*)(&Ash[lr][lc]) = *(const uint4*)(xh + aoff);
        *(uint4*)(&Bsh[lr][lc]) = *(const uint4*)(Bh + boff);
        __syncthreads();

        short8 a0h = *(const short8*)(&Ash[wm + fr][quad * 8]);
        short8 a1h = *(const short8*)(&Ash[wm + 16 + fr][quad * 8]);
        short8 b0h = *(const short8*)(&Bsh[wn + fr][quad * 8]);
        short8 b1h = *(const short8*)(&Bsh[wn + 16 + fr][quad * 8]);

        acc[0][0] = __builtin_amdgcn_mfma_f32_16x16x32_bf16(a0h, b0h, acc[0][0], 0, 0, 0);
        acc[0][1] = __builtin_amdgcn_mfma_f32_16x16x32_bf16(a0h, b1h, acc[0][1], 0, 0, 0);
        acc[1][0] = __builtin_amdgcn_mfma_f32_16x16x32_bf16(a1h, b0h, acc[1][0], 0, 0, 0);
        acc[1][1] = __builtin_amdgcn_mfma_f32_16x16x32_bf16(a1h, b1h, acc[1][1], 0, 0, 0);
        __syncthreads();
    }

    if (widx == 0) {
        #pragma unroll
        for (int tm = 0; tm < 2; tm++)
        #pragma unroll
        for (int tn = 0; tn < 2; tn++)
        #pragma unroll
        for (int r = 0; r < 4; r++) {
            int row = m0 + wm + tm * 16 + quad * 4 + r;
            int col = n0 + wn + tn * 16 + fr;
            Q[(size_t)row * DMODEL + col] = acc[tm][tn][r];
        }
    } else if (widx == 1) {
        // Ktp[(f>>1)*NTOK + n] = pack(bf16(K[n][f_even]), bf16(K[n][f_odd]))
        #pragma unroll
        for (int tm = 0; tm < 2; tm++)
        #pragma unroll
        for (int tn = 0; tn < 2; tn++)
        #pragma unroll
        for (int r = 0; r < 4; r++) {
            float v = acc[tm][tn][r];
            float nb = __shfl_xor(v, 1);
            if (!(fr & 1)) {
                int f = n0 + wn + tn * 16 + fr;
                int n = m0 + wm + tm * 16 + quad * 4 + r;
                unsigned p = (unsigned)bf16bits(v) | ((unsigned)bf16bits(nb) << 16);
                Ktp[(size_t)(f >> 1) * NTOK + n] = p;
            }
        }
    } else {
        // Vp[(row>>1)*DMODEL + col] = pack(bf16(V[row]), bf16(V[row+1]))
        #pragma unroll
        for (int tm = 0; tm < 2; tm++)
        #pragma unroll
        for (int tn = 0; tn < 2; tn++)
        #pragma unroll
        for (int rp = 0; rp < 2; rp++) {
            int row = m0 + wm + tm * 16 + quad * 4 + 2 * rp;
            int col = n0 + wn + tn * 16 + fr;
            unsigned p = (unsigned)bf16bits(acc[tm][tn][2 * rp]) |
                         ((unsigned)bf16bits(acc[tm][tn][2 * rp + 1]) << 16);
            Vp[(size_t)(row >> 1) * DMODEL + col] = p;
        }
    }
}

// ---------------------------------------------------------------------------
// Wo GEMM: C = oh x (Woh + Wol)^T, 64x64 tile, 8 MFMA/iter, f32 store.
// ---------------------------------------------------------------------------
__global__ __launch_bounds__(256) void gemm_wo(
    const __hip_bfloat16* __restrict__ Ah,
    const __hip_bfloat16* __restrict__ Bh, const __hip_bfloat16* __restrict__ Bl,
    float* __restrict__ C)
{
    __shared__ alignas(16) __hip_bfloat16 Ash[64][40];
    __shared__ alignas(16) __hip_bfloat16 Bsh[64][40];
    __shared__ alignas(16) __hip_bfloat16 Bsl[64][40];

    const int n0 = blockIdx.x * 64;
    const int m0 = blockIdx.y * 64;

    const int tid  = threadIdx.x;
    const int wave = tid >> 6;
    const int lane = tid & 63;
    const int lr = tid >> 2;
    const int lc = (tid & 3) * 8;
    const int wm = (wave >> 1) * 32;
    const int wn = (wave & 1) * 32;
    const int fr = lane & 15;
    const int quad = lane >> 4;

    f32x4 acc[2][2] = {};

    for (int k0 = 0; k0 < DMODEL; k0 += 32) {
        const size_t aoff = (size_t)(m0 + lr) * DMODEL + k0 + lc;
        const size_t boff = (size_t)(n0 + lr) * DMODEL + k0 + lc;
        *(uint4*)(&Ash[lr][lc]) = *(const uint4*)(Ah + aoff);
        *(uint4*)(&Bsh[lr][lc]) = *(const uint4*)(Bh + boff);
        *(uint4*)(&Bsl[lr][lc]) = *(const uint4*)(Bl + boff);
        __syncthreads();

        short8 a0h = *(const short8*)(&Ash[wm + fr][quad * 8]);
        short8 a1h = *(const short8*)(&Ash[wm + 16 + fr][quad * 8]);
        short8 b0h = *(const short8*)(&Bsh[wn + fr][quad * 8]);
        short8 b1h = *(const short8*)(&Bsh[wn + 16 + fr][quad * 8]);
        short8 b0l = *(const short8*)(&Bsl[wn + fr][quad * 8]);
        short8 b1l = *(const short8*)(&Bsl[wn + 16 + fr][quad * 8]);

        acc[0][0] = __builtin_amdgcn_mfma_f32_16x16x32_bf16(a0h, b0l, acc[0][0], 0, 0, 0);
        acc[0][1] = __builtin_amdgcn_mfma_f32_16x16x32_bf16(a0h, b1l, acc[0][1], 0, 0, 0);
        acc[1][0] = __builtin_amdgcn_mfma_f32_16x16x32_bf16(a1h, b0l, acc[1][0], 0, 0, 0);
        acc[1][1] = __builtin_amdgcn_mfma_f32_16x16x32_bf16(a1h, b1l, acc[1][1], 0, 0, 0);
        acc[0][0] = __builtin_amdgcn_mfma_f32_16x16x32_bf16(a0h, b0h, acc[0][0], 0, 0, 0);
        acc[0][1] = __builtin_amdgcn_mfma_f32_16x16x32_bf16(a0h, b1h, acc[0][1], 0, 0, 0);
        acc[1][0] = __builtin_amdgcn_mfma_f32_16x16x32_bf16(a1h, b0h, acc[1][0], 0, 0, 0);
        acc[1][1] = __builtin_amdgcn_mfma_f32_16x16x32_bf16(a1h, b1h, acc[1][1], 0, 0, 0);
        __syncthreads();
    }

    #pragma unroll
    for (int tm = 0; tm < 2; tm++)
    #pragma unroll
    for (int tn = 0; tn < 2; tn++)
    #pragma unroll
    for (int r = 0; r < 4; r++) {
        int row = m0 + wm + tm * 16 + quad * 4 + r;
        int col = n0 + wn + tn * 16 + fr;
        C[(size_t)row * DMODEL + col] = acc[tm][tn][r];
    }
}

// ---------------------------------------------------------------------------
// Gate: softmax((x @ Wg^T).reshape(n, 16, 2), axis=-1) -> float2 per (n,h)
// ---------------------------------------------------------------------------
__global__ __launch_bounds__(256) void gate_kernel(
    const float* __restrict__ x,
    const float* __restrict__ Wg,
    float2* __restrict__ gate)
{
    __shared__ float gs[32];
    const int n = blockIdx.x;
    const int wave = threadIdx.x >> 6, lane = threadIdx.x & 63;
    #pragma unroll
    for (int jj = 0; jj < 8; jj++) {
        int j = wave * 8 + jj;
        float s = 0.f;
        #pragma unroll
        for (int t = 0; t < 16; t++) {
            int d = lane + (t << 6);
            s += x[n * DMODEL + d] * Wg[j * DMODEL + d];
        }
        #pragma unroll
        for (int off = 32; off; off >>= 1) s += __shfl_xor(s, off);
        if (lane == 0) gs[j] = s;
    }
    __syncthreads();
    if (threadIdx.x < NHEAD) {
        int h = threadIdx.x;
        float a = gs[2 * h], b = gs[2 * h + 1];
        float m = fmaxf(a, b);
        float ea = expf(a - m), eb = expf(b - m);
        float inv = 1.f / (ea + eb);
        gate[n * NHEAD + h] = make_float2(ea * inv, eb * inv);
    }
}

// ---------------------------------------------------------------------------
// FUSED attention: one wave per (n,h). inter (2 blocks) + causal intra +
// gated blend. Packed bf16 pairs + dot2; readlane broadcasts. Writes oh bf16.
// ---------------------------------------------------------------------------
__global__ __launch_bounds__(256) void attn_fused_kernel(
    const float* __restrict__ Q, const unsigned* __restrict__ Ktp,
    const unsigned* __restrict__ Vp, const int2* __restrict__ idx_t,
    const float2* __restrict__ gate, __hip_bfloat16* __restrict__ oh)
{
    const int wave = threadIdx.x >> 6, lane = threadIdx.x & 63;
    const int gw = blockIdx.x * 4 + wave;   // = n*16 + h
    const int n = gw >> 4, h = gw & 15;
    const int qi = n & 63;
    const int rown = (n >> 6) * CHUNK;
    const int2 sel = idx_t[(h << 10) | n];
    const int r1 = sel.x * CHUNK, r2 = sel.y * CHUNK;

    const float qreg = Q[(size_t)n * DMODEL + h * HDIM + lane];
    const unsigned qpack = packpair(qreg);            // valid at even lanes
    const unsigned* Ktph = Ktp + (size_t)h * 32 * NTOK;

    float s0 = 0.f, s1 = 0.f, si = 0.f;
    #pragma unroll 8
    for (int d2 = 0; d2 < 32; d2++) {
        const unsigned qp = rlu(qpack, 2 * d2);
        const unsigned* row = Ktph + (size_t)d2 * NTOK;
        s0 = dot2bf(row[r1 + lane], qp, s0);
        s1 = dot2bf(row[r2 + lane], qp, s1);
        si = dot2bf(row[rown + lane], qp, si);
    }
    s0 *= 0.125f; s1 *= 0.125f; si *= 0.125f;

    float m = fmaxf(s0, s1);
    #pragma unroll
    for (int off = 32; off; off >>= 1) m = fmaxf(m, __shfl_xor(m, off));
    const float e0 = expf(s0 - m), e1 = expf(s1 - m);
    float sum = e0 + e1;
    #pragma unroll
    for (int off = 32; off; off >>= 1) sum += __shfl_xor(sum, off);

    float sim = (lane > qi) ? -INFINITY : si;
    float mi = sim;
    #pragma unroll
    for (int off = 32; off; off >>= 1) mi = fmaxf(mi, __shfl_xor(mi, off));
    const float ei = (lane > qi) ? 0.f : expf(si - mi);
    float sumi = ei;
    #pragma unroll
    for (int off = 32; off; off >>= 1) sumi += __shfl_xor(sumi, off);

    const unsigned e0p = packpair(e0);
    const unsigned e1p = packpair(e1);
    const unsigned eip = packpair(ei);

    const unsigned* Vph = Vp + h * HDIM + lane;
    float oa = 0.f, ob = 0.f, oi = 0.f;
    const int b1k = r1 >> 1, b2k = r2 >> 1, bik = rown >> 1;
    #pragma unroll 8
    for (int k2 = 0; k2 < 32; k2++) {
        oa = dot2bf(Vph[(size_t)(b1k + k2) * DMODEL], rlu(e0p, 2 * k2), oa);
        ob = dot2bf(Vph[(size_t)(b2k + k2) * DMODEL], rlu(e1p, 2 * k2), ob);
    }
    const int k2max = qi >> 1;                        // wave-uniform
    #pragma unroll 4
    for (int k2 = 0; k2 <= k2max; k2++) {
        oi = dot2bf(Vph[(size_t)(bik + k2) * DMODEL], rlu(eip, 2 * k2), oi);
    }

    const float2 gt = gate[gw];
    const float val = gt.x * ((oa + ob) / sum) + gt.y * (oi / sumi);
    oh[(size_t)n * DMODEL + h * HDIM + lane] = __float2bfloat16(val);
}

// ---------------------------------------------------------------------------
extern "C" void kernel_launch(void* const* d_in, const int* in_sizes, int n_in,
                              void* d_out, int out_size, void* d_ws, size_t ws_size,
                              hipStream_t stream)
{
    const float* x  = (const float*)d_in[0];
    const float* Wq = (const float*)d_in[1];
    const float* Wk = (const float*)d_in[2];
    const float* Wv = (const float*)d_in[3];
    const float* Wg = (const float*)d_in[4];
    const float* Wo = (const float*)d_in[5];

    const size_t M1 = (size_t)NTOK * DMODEL;   // 1M elems

    // workspace layout (~23.5 MB)
    float* Q       = (float*)d_ws;                    // 4 MB
    unsigned* Ktp  = (unsigned*)(Q + M1);             // 2 MB
    unsigned* Vp   = Ktp + (M1 >> 1);                 // 2 MB
    float* Ut      = (float*)(Vp + (M1 >> 1));        // 1 MB
    float* xm      = Ut + (size_t)DMODEL * 256;       // 64 KB
    float* kc      = xm + NBLK * DMODEL;              // 64 KB
    float2* gate   = (float2*)(kc + NBLK * DMODEL);   // 128 KB
    int2* idx_t    = (int2*)(gate + NTOK * NHEAD);    // 128 KB
    __hip_bfloat16* xh  = (__hip_bfloat16*)(idx_t + NTOK * NHEAD);  // 2 MB
    __hip_bfloat16* Wqh = xh + M1;     // 2 MB
    __hip_bfloat16* Wkh = Wqh + M1;    // 2 MB
    __hip_bfloat16* Wvh = Wkh + M1;    // 2 MB
    __hip_bfloat16* Woh = Wvh + M1;    // 2 MB
    __hip_bfloat16* Wol = Woh + M1;    // 2 MB
    __hip_bfloat16* oh  = Wol + M1;    // 2 MB

    cast_all_kernel<<<5 * 1024, 256, 0, stream>>>(
        x, Wq, Wk, Wv, Wo, xh, Wqh, Wkh, Wvh, Woh, Wol);

    xm_kernel<<<64, 256, 0, stream>>>(x, xm);
    kc_gemm_kernel<<<1024, 256, 0, stream>>>(xm, Wk, kc);
    u_kernel<<<256, 256, 0, stream>>>(kc, Wq, Ut);
    gate_kernel<<<NTOK, 256, 0, stream>>>(x, Wg, gate);
    score_top2_kernel<<<256, 256, 0, stream>>>(x, Ut, idx_t);

    dim3 gqkv(48, 16);
    gemm_qkv<<<gqkv, 256, 0, stream>>>(xh, Wqh, Wkh, Wvh, Q, Ktp, Vp);

    attn_fused_kernel<<<NTOK * NHEAD / 4, 256, 0, stream>>>(Q, Ktp, Vp, idx_t, gate, oh);

    dim3 gwo(16, 16);
    gemm_wo<<<gwo, 256, 0, stream>>>(oh, Woh, Wol, (float*)d_out);
}

// Round 15
// 212.790 us; speedup vs baseline: 1.0181x; 1.0181x over previous
//
#include <hip/hip_runtime.h>
#include <hip/hip_bf16.h>
#include <math.h>

// Problem: B=1, N=1024, D=1024, H=16, C=64, TOPK=2, HD=64, G=16
// Inputs (float32): x, Wq, Wk, Wv [1024x1024], Wg[32,1024], Wo[1024,1024]
// Output (float32): [1024,1024]
//
// Selection computed EXACTLY in f32 without Q:
//   kc = (chunk-mean x) @ Wk^T ; U[h,g] = Wq_hblock^T kc ; score = x @ U^T.
// Q/K/V proj plain bf16 MFMA; K/V epilogues emit packed bf16 pairs.
// Wo GEMM: oh x (Woh + Wol). Attention: wave per (n,h), dot2 pairs, readlane.
// DAG: 6 launches. BK=64 K-loops (16 iters) to halve barrier-serial chain.

typedef __attribute__((ext_vector_type(8))) short short8;   // 8 bf16 = 4 VGPRs
typedef __attribute__((ext_vector_type(4))) float f32x4;
typedef __attribute__((ext_vector_type(2))) __bf16 bf16x2v;

#define NTOK 1024
#define DMODEL 1024
#define NHEAD 16
#define HDIM 64
#define CHUNK 64
#define NBLK 16

__device__ __forceinline__ unsigned rlu(unsigned v, int l)
{
    return (unsigned)__builtin_amdgcn_readlane((int)v, l);
}

__device__ __forceinline__ unsigned short bf16bits(float v)
{
    __hip_bfloat16 h = __float2bfloat16(v);
    return __builtin_bit_cast(unsigned short, h);
}

__device__ __forceinline__ float dot2bf(unsigned a, unsigned b, float acc)
{
#if __has_builtin(__builtin_amdgcn_fdot2_f32_bf16)
    return __builtin_amdgcn_fdot2_f32_bf16(
        __builtin_bit_cast(bf16x2v, a), __builtin_bit_cast(bf16x2v, b), acc, false);
#else
    float a0 = __uint_as_float(a << 16), a1 = __uint_as_float(a & 0xffff0000u);
    float b0 = __uint_as_float(b << 16), b1 = __uint_as_float(b & 0xffff0000u);
    return acc + a0 * b0 + a1 * b1;
#endif
}

// pack (own, lane^1) bf16 bits into a uint; valid at EVEN lanes (own=low)
__device__ __forceinline__ unsigned packpair(float v)
{
    unsigned b = bf16bits(v);
    unsigned nb = (unsigned)__shfl_xor((int)b, 1) & 0xffffu;
    return b | (nb << 16);
}

// ---------------------------------------------------------------------------
// A: prep. blockIdx roles: [0,5120) casts (which = bid>>10: x,Wq,Wk,Wv hi;
// 4 = Wo split), [5120,5184) xm, [5184,6208) gate.
// ---------------------------------------------------------------------------
__global__ __launch_bounds__(256) void prep_kernel(
    const float* __restrict__ x,  const float* __restrict__ Wq,
    const float* __restrict__ Wk, const float* __restrict__ Wv,
    const float* __restrict__ Wo, const float* __restrict__ Wg,
    __hip_bfloat16* __restrict__ xh,  __hip_bfloat16* __restrict__ Wqh,
    __hip_bfloat16* __restrict__ Wkh, __hip_bfloat16* __restrict__ Wvh,
    __hip_bfloat16* __restrict__ Woh, __hip_bfloat16* __restrict__ Wol,
    float* __restrict__ xm, float2* __restrict__ gate)
{
    __shared__ float gs[32];
    const int bid = blockIdx.x;
    if (bid < 5120) {
        const int which = bid >> 10;
        const int b = bid & 1023;
        const int i = (b * 256 + threadIdx.x) * 4;
        const float* in; __hip_bfloat16 *hi, *lo = nullptr;
        if (which == 0)      { in = x;  hi = xh;  }
        else if (which == 1) { in = Wq; hi = Wqh; }
        else if (which == 2) { in = Wk; hi = Wkh; }
        else if (which == 3) { in = Wv; hi = Wvh; }
        else                 { in = Wo; hi = Woh; lo = Wol; }
        float4 v = *(const float4*)(in + i);
        float vv[4] = {v.x, v.y, v.z, v.w};
        __hip_bfloat16 h[4], l[4];
        #pragma unroll
        for (int j = 0; j < 4; j++) {
            h[j] = __float2bfloat16(vv[j]);
            l[j] = __float2bfloat16(vv[j] - __bfloat162float(h[j]));
        }
        *(uint2*)(hi + i) = *(uint2*)h;
        if (lo) *(uint2*)(lo + i) = *(uint2*)l;
    } else if (bid < 5184) {
        const int b = bid - 5120;
        const int g = b >> 2;
        const int f = (b & 3) * 256 + threadIdx.x;
        float s = 0.f;
        #pragma unroll 8
        for (int c = 0; c < CHUNK; c++) s += x[(size_t)(g * CHUNK + c) * DMODEL + f];
        xm[g * DMODEL + f] = s * (1.0f / CHUNK);
    } else {
        const int n = bid - 5184;
        const int wave = threadIdx.x >> 6, lane = threadIdx.x & 63;
        #pragma unroll
        for (int jj = 0; jj < 8; jj++) {
            int j = wave * 8 + jj;
            float s = 0.f;
            #pragma unroll
            for (int t = 0; t < 16; t++) {
                int d = lane + (t << 6);
                s += x[n * DMODEL + d] * Wg[j * DMODEL + d];
            }
            #pragma unroll
            for (int off = 32; off; off >>= 1) s += __shfl_xor(s, off);
            if (lane == 0) gs[j] = s;
        }
        __syncthreads();
        if (threadIdx.x < NHEAD) {
            int h = threadIdx.x;
            float a = gs[2 * h], b = gs[2 * h + 1];
            float m = fmaxf(a, b);
            float ea = expf(a - m), eb = expf(b - m);
            float inv = 1.f / (ea + eb);
            gate[n * NHEAD + h] = make_float2(ea * inv, eb * inv);
        }
    }
}

// ---------------------------------------------------------------------------
// B: kc = xm @ Wk^T (exact f32). One block per f; (g = tid>>4, sub = tid&15).
// ---------------------------------------------------------------------------
__global__ __launch_bounds__(256) void kc_gemm_kernel(
    const float* __restrict__ xm, const float* __restrict__ Wk,
    float* __restrict__ kc)
{
    const int f = blockIdx.x;
    const int g = threadIdx.x >> 4;
    const int sub = threadIdx.x & 15;
    const float* wrow = Wk + (size_t)f * DMODEL;
    float s = 0.f;
    #pragma unroll 16
    for (int i = 0; i < 64; i++) {
        int e = i * 16 + sub;
        s += xm[g * DMODEL + e] * wrow[e];
    }
    #pragma unroll
    for (int off = 8; off; off >>= 1) s += __shfl_xor(s, off);
    if (sub == 0) kc[g * DMODEL + f] = s;
}

// ---------------------------------------------------------------------------
// C: Ut[f][(h<<4)|g] = sum_d kc[g][h*64+d] * Wq[h*64+d][f]  (exact f32)
// ---------------------------------------------------------------------------
__global__ __launch_bounds__(256) void u_kernel(
    const float* __restrict__ kc, const float* __restrict__ Wq,
    float* __restrict__ Ut)
{
    __shared__ float kcs[64];
    const int h = blockIdx.x >> 4, g = blockIdx.x & 15;
    if (threadIdx.x < 64) kcs[threadIdx.x] = kc[g * DMODEL + h * HDIM + threadIdx.x];
    __syncthreads();
    const int col = (h << 4) | g;
    for (int f = threadIdx.x; f < DMODEL; f += 256) {
        float s = 0.f;
        #pragma unroll 16
        for (int d = 0; d < 64; d++)
            s += kcs[d] * Wq[(size_t)(h * HDIM + d) * DMODEL + f];
        Ut[(size_t)f * 256 + col] = s;
    }
}

// ---------------------------------------------------------------------------
// D: qkv GEMMs (blocks [0,768), BK=64) + score/top-2 (blocks [768,1024)).
// qkv: widx = b>>8 (0:Q f32, 1:K->Ktp packed transposed, 2:V->Vp row-pairs).
// score: exact f32 x @ Ut, masked top-2 (ties->lowest; all-masked->(0,1)).
// ---------------------------------------------------------------------------
__global__ __launch_bounds__(256) void qkv_score_kernel(
    const __hip_bfloat16* __restrict__ xh,
    const __hip_bfloat16* __restrict__ Wqh, const __hip_bfloat16* __restrict__ Wkh,
    const __hip_bfloat16* __restrict__ Wvh,
    const float* __restrict__ x, const float* __restrict__ Ut,
    float* __restrict__ Q, unsigned* __restrict__ Ktp, unsigned* __restrict__ Vp,
    int2* __restrict__ idx_t)
{
    __shared__ uint4 smem4[20480 / 16];     // 20 KB shared scratch, 16B-aligned
    char* smem = (char*)smem4;
    const int b = blockIdx.x;

    if (b < 768) {
        __hip_bfloat16 (*Ash)[72] = (__hip_bfloat16(*)[72])smem;
        __hip_bfloat16 (*Bsh)[72] = (__hip_bfloat16(*)[72])(smem + 9216);

        const int widx = b >> 8;
        const int t = b & 255;
        const __hip_bfloat16* __restrict__ Bh =
            (widx == 0) ? Wqh : (widx == 1) ? Wkh : Wvh;
        const int n0 = (t & 15) * 64;
        const int m0 = (t >> 4) * 64;

        const int tid  = threadIdx.x;
        const int wave = tid >> 6;
        const int lane = tid & 63;
        const int lr = tid >> 2;
        const int lc = (tid & 3) * 16;
        const int wm = (wave >> 1) * 32;
        const int wn = (wave & 1) * 32;
        const int fr = lane & 15;
        const int quad = lane >> 4;

        f32x4 acc[2][2] = {};

        for (int k0 = 0; k0 < DMODEL; k0 += 64) {
            const size_t aoff = (size_t)(m0 + lr) * DMODEL + k0 + lc;
            const size_t boff = (size_t)(n0 + lr) * DMODEL + k0 + lc;
            *(uint4*)(&Ash[lr][lc])     = *(const uint4*)(xh + aoff);
            *(uint4*)(&Ash[lr][lc + 8]) = *(const uint4*)(xh + aoff + 8);
            *(uint4*)(&Bsh[lr][lc])     = *(const uint4*)(Bh + boff);
            *(uint4*)(&Bsh[lr][lc + 8]) = *(const uint4*)(Bh + boff + 8);
            __syncthreads();

            #pragma unroll
            for (int hk = 0; hk < 2; hk++) {
                const int kc0 = hk * 32 + quad * 8;
                short8 a0 = *(const short8*)(&Ash[wm + fr][kc0]);
                short8 a1 = *(const short8*)(&Ash[wm + 16 + fr][kc0]);
                short8 b0 = *(const short8*)(&Bsh[wn + fr][kc0]);
                short8 b1 = *(const short8*)(&Bsh[wn + 16 + fr][kc0]);
                acc[0][0] = __builtin_amdgcn_mfma_f32_16x16x32_bf16(a0, b0, acc[0][0], 0, 0, 0);
                acc[0][1] = __builtin_amdgcn_mfma_f32_16x16x32_bf16(a0, b1, acc[0][1], 0, 0, 0);
                acc[1][0] = __builtin_amdgcn_mfma_f32_16x16x32_bf16(a1, b0, acc[1][0], 0, 0, 0);
                acc[1][1] = __builtin_amdgcn_mfma_f32_16x16x32_bf16(a1, b1, acc[1][1], 0, 0, 0);
            }
            __syncthreads();
        }

        if (widx == 0) {
            #pragma unroll
            for (int tm = 0; tm < 2; tm++)
            #pragma unroll
            for (int tn = 0; tn < 2; tn++)
            #pragma unroll
            for (int r = 0; r < 4; r++) {
                int row = m0 + wm + tm * 16 + quad * 4 + r;
                int col = n0 + wn + tn * 16 + fr;
                Q[(size_t)row * DMODEL + col] = acc[tm][tn][r];
            }
        } else if (widx == 1) {
            #pragma unroll
            for (int tm = 0; tm < 2; tm++)
            #pragma unroll
            for (int tn = 0; tn < 2; tn++)
            #pragma unroll
            for (int r = 0; r < 4; r++) {
                float v = acc[tm][tn][r];
                float nb = __shfl_xor(v, 1);
                if (!(fr & 1)) {
                    int f = n0 + wn + tn * 16 + fr;
                    int n = m0 + wm + tm * 16 + quad * 4 + r;
                    unsigned p = (unsigned)bf16bits(v) | ((unsigned)bf16bits(nb) << 16);
                    Ktp[(size_t)(f >> 1) * NTOK + n] = p;
                }
            }
        } else {
            #pragma unroll
            for (int tm = 0; tm < 2; tm++)
            #pragma unroll
            for (int tn = 0; tn < 2; tn++)
            #pragma unroll
            for (int rp = 0; rp < 2; rp++) {
                int row = m0 + wm + tm * 16 + quad * 4 + 2 * rp;
                int col = n0 + wn + tn * 16 + fr;
                unsigned p = (unsigned)bf16bits(acc[tm][tn][2 * rp]) |
                             ((unsigned)bf16bits(acc[tm][tn][2 * rp + 1]) << 16);
                Vp[(size_t)(row >> 1) * DMODEL + col] = p;
            }
        }
    } else {
        float (*Xs)[1024] = (float(*)[1024])smem;            // 16 KB
        float (*sc)[256]  = (float(*)[256])(smem + 16384);   // 4 KB
        const int n0 = (b - 768) * 4;
        for (int i = threadIdx.x; i < 4 * 1024; i += 256) {
            int j = i >> 10, f = i & 1023;
            Xs[j][f] = x[(size_t)(n0 + j) * DMODEL + f];
        }
        __syncthreads();
        const int t = threadIdx.x;
        float a0 = 0.f, a1 = 0.f, a2 = 0.f, a3 = 0.f;
        #pragma unroll 8
        for (int f = 0; f < DMODEL; f++) {
            float u = Ut[(size_t)f * 256 + t];
            a0 += Xs[0][f] * u;
            a1 += Xs[1][f] * u;
            a2 += Xs[2][f] * u;
            a3 += Xs[3][f] * u;
        }
        sc[0][t] = a0; sc[1][t] = a1; sc[2][t] = a2; sc[3][t] = a3;
        __syncthreads();
        if (t < 64) {
            const int j = t >> 4, h = t & 15;
            const int n = n0 + j;
            float s[NBLK];
            #pragma unroll
            for (int g = 0; g < NBLK; g++)
                s[g] = (n >= (g << 6)) ? -INFINITY : sc[j][h * 16 + g];
            int i1 = -1; float b1 = -INFINITY;
            #pragma unroll
            for (int g = 0; g < NBLK; g++) if (i1 < 0 || s[g] > b1) { b1 = s[g]; i1 = g; }
            int i2 = -1; float b2 = -INFINITY;
            #pragma unroll
            for (int g = 0; g < NBLK; g++) { if (g == i1) continue; if (i2 < 0 || s[g] > b2) { b2 = s[g]; i2 = g; } }
            idx_t[(h << 10) | n] = make_int2(i1, i2);
        }
    }
}

// ---------------------------------------------------------------------------
// E: FUSED attention: one wave per (n,h). inter (2 blocks) + causal intra +
// gated blend. Packed bf16 pairs + dot2; readlane broadcasts. Writes oh bf16.
// ---------------------------------------------------------------------------
__global__ __launch_bounds__(256) void attn_fused_kernel(
    const float* __restrict__ Q, const unsigned* __restrict__ Ktp,
    const unsigned* __restrict__ Vp, const int2* __restrict__ idx_t,
    const float2* __restrict__ gate, __hip_bfloat16* __restrict__ oh)
{
    const int wave = threadIdx.x >> 6, lane = threadIdx.x & 63;
    const int gw = blockIdx.x * 4 + wave;   // = n*16 + h
    const int n = gw >> 4, h = gw & 15;
    const int qi = n & 63;
    const int rown = (n >> 6) * CHUNK;
    const int2 sel = idx_t[(h << 10) | n];
    const int r1 = sel.x * CHUNK, r2 = sel.y * CHUNK;

    const float qreg = Q[(size_t)n * DMODEL + h * HDIM + lane];
    const unsigned qpack = packpair(qreg);            // valid at even lanes
    const unsigned* Ktph = Ktp + (size_t)h * 32 * NTOK;

    float s0 = 0.f, s1 = 0.f, si = 0.f;
    #pragma unroll 8
    for (int d2 = 0; d2 < 32; d2++) {
        const unsigned qp = rlu(qpack, 2 * d2);
        const unsigned* row = Ktph + (size_t)d2 * NTOK;
        s0 = dot2bf(row[r1 + lane], qp, s0);
        s1 = dot2bf(row[r2 + lane], qp, s1);
        si = dot2bf(row[rown + lane], qp, si);
    }
    s0 *= 0.125f; s1 *= 0.125f; si *= 0.125f;

    float m = fmaxf(s0, s1);
    #pragma unroll
    for (int off = 32; off; off >>= 1) m = fmaxf(m, __shfl_xor(m, off));
    const float e0 = expf(s0 - m), e1 = expf(s1 - m);
    float sum = e0 + e1;
    #pragma unroll
    for (int off = 32; off; off >>= 1) sum += __shfl_xor(sum, off);

    float sim = (lane > qi) ? -INFINITY : si;
    float mi = sim;
    #pragma unroll
    for (int off = 32; off; off >>= 1) mi = fmaxf(mi, __shfl_xor(mi, off));
    const float ei = (lane > qi) ? 0.f : expf(si - mi);
    float sumi = ei;
    #pragma unroll
    for (int off = 32; off; off >>= 1) sumi += __shfl_xor(sumi, off);

    const unsigned e0p = packpair(e0);
    const unsigned e1p = packpair(e1);
    const unsigned eip = packpair(ei);

    const unsigned* Vph = Vp + h * HDIM + lane;
    float oa = 0.f, ob = 0.f, oi = 0.f;
    const int b1k = r1 >> 1, b2k = r2 >> 1, bik = rown >> 1;
    #pragma unroll 8
    for (int k2 = 0; k2 < 32; k2++) {
        oa = dot2bf(Vph[(size_t)(b1k + k2) * DMODEL], rlu(e0p, 2 * k2), oa);
        ob = dot2bf(Vph[(size_t)(b2k + k2) * DMODEL], rlu(e1p, 2 * k2), ob);
    }
    const int k2max = qi >> 1;                        // wave-uniform
    #pragma unroll 4
    for (int k2 = 0; k2 <= k2max; k2++) {
        oi = dot2bf(Vph[(size_t)(bik + k2) * DMODEL], rlu(eip, 2 * k2), oi);
    }

    const float2 gt = gate[gw];
    const float val = gt.x * ((oa + ob) / sum) + gt.y * (oi / sumi);
    oh[(size_t)n * DMODEL + h * HDIM + lane] = __float2bfloat16(val);
}

// ---------------------------------------------------------------------------
// F: Wo GEMM: C = oh x (Woh + Wol)^T, 64x64 tile, BK=64, f32 store.
// ---------------------------------------------------------------------------
__global__ __launch_bounds__(256) void gemm_wo(
    const __hip_bfloat16* __restrict__ Ah,
    const __hip_bfloat16* __restrict__ Bh, const __hip_bfloat16* __restrict__ Bl,
    float* __restrict__ C)
{
    __shared__ alignas(16) __hip_bfloat16 Ash[64][72];
    __shared__ alignas(16) __hip_bfloat16 Bsh[64][72];
    __shared__ alignas(16) __hip_bfloat16 Bsl[64][72];

    const int n0 = blockIdx.x * 64;
    const int m0 = blockIdx.y * 64;

    const int tid  = threadIdx.x;
    const int wave = tid >> 6;
    const int lane = tid & 63;
    const int lr = tid >> 2;
    const int lc = (tid & 3) * 16;
    const int wm = (wave >> 1) * 32;
    const int wn = (wave & 1) * 32;
    const int fr = lane & 15;
    const int quad = lane >> 4;

    f32x4 acc[2][2] = {};

    for (int k0 = 0; k0 < DMODEL; k0 += 64) {
        const size_t aoff = (size_t)(m0 + lr) * DMODEL + k0 + lc;
        const size_t boff = (size_t)(n0 + lr) * DMODEL + k0 + lc;
        *(uint4*)(&Ash[lr][lc])     = *(const uint4*)(Ah + aoff);
        *(uint4*)(&Ash[lr][lc + 8]) = *(const uint4*)(Ah + aoff + 8);
        *(uint4*)(&Bsh[lr][lc])     = *(const uint4*)(Bh + boff);
        *(uint4*)(&Bsh[lr][lc + 8]) = *(const uint4*)(Bh + boff + 8);
        *(uint4*)(&Bsl[lr][lc])     = *(const uint4*)(Bl + boff);
        *(uint4*)(&Bsl[lr][lc + 8]) = *(const uint4*)(Bl + boff + 8);
        __syncthreads();

        #pragma unroll
        for (int hk = 0; hk < 2; hk++) {
            const int kc0 = hk * 32 + quad * 8;
            short8 a0 = *(const short8*)(&Ash[wm + fr][kc0]);
            short8 a1 = *(const short8*)(&Ash[wm + 16 + fr][kc0]);
            short8 b0h = *(const short8*)(&Bsh[wn + fr][kc0]);
            short8 b1h = *(const short8*)(&Bsh[wn + 16 + fr][kc0]);
            short8 b0l = *(const short8*)(&Bsl[wn + fr][kc0]);
            short8 b1l = *(const short8*)(&Bsl[wn + 16 + fr][kc0]);
            acc[0][0] = __builtin_amdgcn_mfma_f32_16x16x32_bf16(a0, b0l, acc[0][0], 0, 0, 0);
            acc[0][1] = __builtin_amdgcn_mfma_f32_16x16x32_bf16(a0, b1l, acc[0][1], 0, 0, 0);
            acc[1][0] = __builtin_amdgcn_mfma_f32_16x16x32_bf16(a1, b0l, acc[1][0], 0, 0, 0);
            acc[1][1] = __builtin_amdgcn_mfma_f32_16x16x32_bf16(a1, b1l, acc[1][1], 0, 0, 0);
            acc[0][0] = __builtin_amdgcn_mfma_f32_16x16x32_bf16(a0, b0h, acc[0][0], 0, 0, 0);
            acc[0][1] = __builtin_amdgcn_mfma_f32_16x16x32_bf16(a0, b1h, acc[0][1], 0, 0, 0);
            acc[1][0] = __builtin_amdgcn_mfma_f32_16x16x32_bf16(a1, b0h, acc[1][0], 0, 0, 0);
            acc[1][1] = __builtin_amdgcn_mfma_f32_16x16x32_bf16(a1, b1h, acc[1][1], 0, 0, 0);
        }
        __syncthreads();
    }

    #pragma unroll
    for (int tm = 0; tm < 2; tm++)
    #pragma unroll
    for (int tn = 0; tn < 2; tn++)
    #pragma unroll
    for (int r = 0; r < 4; r++) {
        int row = m0 + wm + tm * 16 + quad * 4 + r;
        int col = n0 + wn + tn * 16 + fr;
        C[(size_t)row * DMODEL + col] = acc[tm][tn][r];
    }
}

// ---------------------------------------------------------------------------
extern "C" void kernel_launch(void* const* d_in, const int* in_sizes, int n_in,
                              void* d_out, int out_size, void* d_ws, size_t ws_size,
                              hipStream_t stream)
{
    const float* x  = (const float*)d_in[0];
    const float* Wq = (const float*)d_in[1];
    const float* Wk = (const float*)d_in[2];
    const float* Wv = (const float*)d_in[3];
    const float* Wg = (const float*)d_in[4];
    const float* Wo = (const float*)d_in[5];

    const size_t M1 = (size_t)NTOK * DMODEL;   // 1M elems

    // workspace layout (~23.5 MB)
    float* Q       = (float*)d_ws;                    // 4 MB
    unsigned* Ktp  = (unsigned*)(Q + M1);             // 2 MB
    unsigned* Vp   = Ktp + (M1 >> 1);                 // 2 MB
    float* Ut      = (float*)(Vp + (M1 >> 1));        // 1 MB
    float* xm      = Ut + (size_t)DMODEL * 256;       // 64 KB
    float* kc      = xm + NBLK * DMODEL;              // 64 KB
    float2* gate   = (float2*)(kc + NBLK * DMODEL);   // 128 KB
    int2* idx_t    = (int2*)(gate + NTOK * NHEAD);    // 128 KB
    __hip_bfloat16* xh  = (__hip_bfloat16*)(idx_t + NTOK * NHEAD);  // 2 MB
    __hip_bfloat16* Wqh = xh + M1;     // 2 MB
    __hip_bfloat16* Wkh = Wqh + M1;    // 2 MB
    __hip_bfloat16* Wvh = Wkh + M1;    // 2 MB
    __hip_bfloat16* Woh = Wvh + M1;    // 2 MB
    __hip_bfloat16* Wol = Woh + M1;    // 2 MB
    __hip_bfloat16* oh  = Wol + M1;    // 2 MB

    prep_kernel<<<6208, 256, 0, stream>>>(
        x, Wq, Wk, Wv, Wo, Wg, xh, Wqh, Wkh, Wvh, Woh, Wol, xm, gate);

    kc_gemm_kernel<<<1024, 256, 0, stream>>>(xm, Wk, kc);
    u_kernel<<<256, 256, 0, stream>>>(kc, Wq, Ut);

    qkv_score_kernel<<<1024, 256, 0, stream>>>(
        xh, Wqh, Wkh, Wvh, x, Ut, Q, Ktp, Vp, idx_t);

    attn_fused_kernel<<<NTOK * NHEAD / 4, 256, 0, stream>>>(Q, Ktp, Vp, idx_t, gate, oh);

    dim3 gwo(16, 16);
    gemm_wo<<<gwo, 256, 0, stream>>>(oh, Woh, Wol, (float*)d_out);
}

// Round 16
// 212.072 us; speedup vs baseline: 1.0216x; 1.0034x over previous
//
#include <hip/hip_runtime.h>
#include <hip/hip_bf16.h>
#include <math.h>

// Problem: B=1, N=1024, D=1024, H=16, C=64, TOPK=2, HD=64, G=16
// Inputs (float32): x, Wq, Wk, Wv [1024x1024], Wg[32,1024], Wo[1024,1024]
// Output (float32): [1024,1024]
//
// Selection computed EXACTLY in f32 without Q:
//   kc = (chunk-mean x) @ Wk^T ; U[h,g] = Wq_hblock^T kc ; score = x @ U^T.
// Q/K/V proj plain bf16 MFMA; K/V epilogues emit packed bf16 pairs.
// Wo GEMM: oh x (Woh + Wol). Attention: wave per (n,h), dot2 pairs, readlane.
// DAG: 6 launches. Co-launched kernel D: score FIRST (1024 blocks, 1 token
// each — the latency-bound long pole needs max TLP), then 768 GEMM blocks.

typedef __attribute__((ext_vector_type(8))) short short8;   // 8 bf16 = 4 VGPRs
typedef __attribute__((ext_vector_type(4))) float f32x4;
typedef __attribute__((ext_vector_type(2))) __bf16 bf16x2v;

#define NTOK 1024
#define DMODEL 1024
#define NHEAD 16
#define HDIM 64
#define CHUNK 64
#define NBLK 16

__device__ __forceinline__ unsigned rlu(unsigned v, int l)
{
    return (unsigned)__builtin_amdgcn_readlane((int)v, l);
}

__device__ __forceinline__ unsigned short bf16bits(float v)
{
    __hip_bfloat16 h = __float2bfloat16(v);
    return __builtin_bit_cast(unsigned short, h);
}

__device__ __forceinline__ float dot2bf(unsigned a, unsigned b, float acc)
{
#if __has_builtin(__builtin_amdgcn_fdot2_f32_bf16)
    return __builtin_amdgcn_fdot2_f32_bf16(
        __builtin_bit_cast(bf16x2v, a), __builtin_bit_cast(bf16x2v, b), acc, false);
#else
    float a0 = __uint_as_float(a << 16), a1 = __uint_as_float(a & 0xffff0000u);
    float b0 = __uint_as_float(b << 16), b1 = __uint_as_float(b & 0xffff0000u);
    return acc + a0 * b0 + a1 * b1;
#endif
}

// pack (own, lane^1) bf16 bits into a uint; valid at EVEN lanes (own=low)
__device__ __forceinline__ unsigned packpair(float v)
{
    unsigned b = bf16bits(v);
    unsigned nb = (unsigned)__shfl_xor((int)b, 1) & 0xffffu;
    return b | (nb << 16);
}

// ---------------------------------------------------------------------------
// A: prep. blockIdx roles: [0,5120) casts (which = bid>>10: x,Wq,Wk,Wv hi;
// 4 = Wo split), [5120,5184) xm, [5184,6208) gate.
// ---------------------------------------------------------------------------
__global__ __launch_bounds__(256) void prep_kernel(
    const float* __restrict__ x,  const float* __restrict__ Wq,
    const float* __restrict__ Wk, const float* __restrict__ Wv,
    const float* __restrict__ Wo, const float* __restrict__ Wg,
    __hip_bfloat16* __restrict__ xh,  __hip_bfloat16* __restrict__ Wqh,
    __hip_bfloat16* __restrict__ Wkh, __hip_bfloat16* __restrict__ Wvh,
    __hip_bfloat16* __restrict__ Woh, __hip_bfloat16* __restrict__ Wol,
    float* __restrict__ xm, float2* __restrict__ gate)
{
    __shared__ float gs[32];
    const int bid = blockIdx.x;
    if (bid < 5120) {
        const int which = bid >> 10;
        const int b = bid & 1023;
        const int i = (b * 256 + threadIdx.x) * 4;
        const float* in; __hip_bfloat16 *hi, *lo = nullptr;
        if (which == 0)      { in = x;  hi = xh;  }
        else if (which == 1) { in = Wq; hi = Wqh; }
        else if (which == 2) { in = Wk; hi = Wkh; }
        else if (which == 3) { in = Wv; hi = Wvh; }
        else                 { in = Wo; hi = Woh; lo = Wol; }
        float4 v = *(const float4*)(in + i);
        float vv[4] = {v.x, v.y, v.z, v.w};
        __hip_bfloat16 h[4], l[4];
        #pragma unroll
        for (int j = 0; j < 4; j++) {
            h[j] = __float2bfloat16(vv[j]);
            l[j] = __float2bfloat16(vv[j] - __bfloat162float(h[j]));
        }
        *(uint2*)(hi + i) = *(uint2*)h;
        if (lo) *(uint2*)(lo + i) = *(uint2*)l;
    } else if (bid < 5184) {
        const int b = bid - 5120;
        const int g = b >> 2;
        const int f = (b & 3) * 256 + threadIdx.x;
        float s = 0.f;
        #pragma unroll 8
        for (int c = 0; c < CHUNK; c++) s += x[(size_t)(g * CHUNK + c) * DMODEL + f];
        xm[g * DMODEL + f] = s * (1.0f / CHUNK);
    } else {
        const int n = bid - 5184;
        const int wave = threadIdx.x >> 6, lane = threadIdx.x & 63;
        #pragma unroll
        for (int jj = 0; jj < 8; jj++) {
            int j = wave * 8 + jj;
            float s = 0.f;
            #pragma unroll
            for (int t = 0; t < 16; t++) {
                int d = lane + (t << 6);
                s += x[n * DMODEL + d] * Wg[j * DMODEL + d];
            }
            #pragma unroll
            for (int off = 32; off; off >>= 1) s += __shfl_xor(s, off);
            if (lane == 0) gs[j] = s;
        }
        __syncthreads();
        if (threadIdx.x < NHEAD) {
            int h = threadIdx.x;
            float a = gs[2 * h], b = gs[2 * h + 1];
            float m = fmaxf(a, b);
            float ea = expf(a - m), eb = expf(b - m);
            float inv = 1.f / (ea + eb);
            gate[n * NHEAD + h] = make_float2(ea * inv, eb * inv);
        }
    }
}

// ---------------------------------------------------------------------------
// B: kc = xm @ Wk^T (exact f32). One block per f; (g = tid>>4, sub = tid&15).
// ---------------------------------------------------------------------------
__global__ __launch_bounds__(256) void kc_gemm_kernel(
    const float* __restrict__ xm, const float* __restrict__ Wk,
    float* __restrict__ kc)
{
    const int f = blockIdx.x;
    const int g = threadIdx.x >> 4;
    const int sub = threadIdx.x & 15;
    const float* wrow = Wk + (size_t)f * DMODEL;
    float s = 0.f;
    #pragma unroll 16
    for (int i = 0; i < 64; i++) {
        int e = i * 16 + sub;
        s += xm[g * DMODEL + e] * wrow[e];
    }
    #pragma unroll
    for (int off = 8; off; off >>= 1) s += __shfl_xor(s, off);
    if (sub == 0) kc[g * DMODEL + f] = s;
}

// ---------------------------------------------------------------------------
// C: Ut[f][(h<<4)|g] = sum_d kc[g][h*64+d] * Wq[h*64+d][f]  (exact f32)
// ---------------------------------------------------------------------------
__global__ __launch_bounds__(256) void u_kernel(
    const float* __restrict__ kc, const float* __restrict__ Wq,
    float* __restrict__ Ut)
{
    __shared__ float kcs[64];
    const int h = blockIdx.x >> 4, g = blockIdx.x & 15;
    if (threadIdx.x < 64) kcs[threadIdx.x] = kc[g * DMODEL + h * HDIM + threadIdx.x];
    __syncthreads();
    const int col = (h << 4) | g;
    for (int f = threadIdx.x; f < DMODEL; f += 256) {
        float s = 0.f;
        #pragma unroll 16
        for (int d = 0; d < 64; d++)
            s += kcs[d] * Wq[(size_t)(h * HDIM + d) * DMODEL + f];
        Ut[(size_t)f * 256 + col] = s;
    }
}

// ---------------------------------------------------------------------------
// D: score/top-2 (blocks [0,1024), 1 token each — long pole goes first, max
// TLP) + qkv GEMMs (blocks [1024,1792), BK=64).
// score: exact f32 x @ Ut, masked top-2 (ties->lowest; all-masked->(0,1)).
// qkv: widx (0:Q f32, 1:K->Ktp packed transposed, 2:V->Vp row-pairs).
// ---------------------------------------------------------------------------
__global__ __launch_bounds__(256) void qkv_score_kernel(
    const __hip_bfloat16* __restrict__ xh,
    const __hip_bfloat16* __restrict__ Wqh, const __hip_bfloat16* __restrict__ Wkh,
    const __hip_bfloat16* __restrict__ Wvh,
    const float* __restrict__ x, const float* __restrict__ Ut,
    float* __restrict__ Q, unsigned* __restrict__ Ktp, unsigned* __restrict__ Vp,
    int2* __restrict__ idx_t)
{
    __shared__ uint4 smem4[20480 / 16];     // 20 KB shared scratch, 16B-aligned
    char* smem = (char*)smem4;
    const int b = blockIdx.x;

    if (b < 1024) {
        // ---- score/top-2 for token n = b ----
        float* Xs = (float*)smem;                 // 4 KB
        float* sc = (float*)(smem + 4096);        // 1 KB
        const int n = b;
        {
            const int i = threadIdx.x * 4;
            *(float4*)(Xs + i) = *(const float4*)(x + (size_t)n * DMODEL + i);
        }
        __syncthreads();
        const int t = threadIdx.x;                // t = (h<<4)|g
        float acc = 0.f;
        #pragma unroll 16
        for (int f = 0; f < DMODEL; f++) {
            acc += Xs[f] * Ut[(size_t)f * 256 + t];
        }
        sc[t] = acc;
        __syncthreads();
        if (t < NHEAD) {
            const int h = t;
            float s[NBLK];
            #pragma unroll
            for (int g = 0; g < NBLK; g++)
                s[g] = (n >= (g << 6)) ? -INFINITY : sc[h * 16 + g];
            int i1 = -1; float b1 = -INFINITY;
            #pragma unroll
            for (int g = 0; g < NBLK; g++) if (i1 < 0 || s[g] > b1) { b1 = s[g]; i1 = g; }
            int i2 = -1; float b2 = -INFINITY;
            #pragma unroll
            for (int g = 0; g < NBLK; g++) { if (g == i1) continue; if (i2 < 0 || s[g] > b2) { b2 = s[g]; i2 = g; } }
            idx_t[(h << 10) | n] = make_int2(i1, i2);
        }
    } else {
        // ---- QKV GEMM ----
        __hip_bfloat16 (*Ash)[72] = (__hip_bfloat16(*)[72])smem;
        __hip_bfloat16 (*Bsh)[72] = (__hip_bfloat16(*)[72])(smem + 9216);

        const int bb = b - 1024;
        const int widx = bb >> 8;
        const int t = bb & 255;
        const __hip_bfloat16* __restrict__ Bh =
            (widx == 0) ? Wqh : (widx == 1) ? Wkh : Wvh;
        const int n0 = (t & 15) * 64;
        const int m0 = (t >> 4) * 64;

        const int tid  = threadIdx.x;
        const int wave = tid >> 6;
        const int lane = tid & 63;
        const int lr = tid >> 2;
        const int lc = (tid & 3) * 16;
        const int wm = (wave >> 1) * 32;
        const int wn = (wave & 1) * 32;
        const int fr = lane & 15;
        const int quad = lane >> 4;

        f32x4 acc[2][2] = {};

        for (int k0 = 0; k0 < DMODEL; k0 += 64) {
            const size_t aoff = (size_t)(m0 + lr) * DMODEL + k0 + lc;
            const size_t boff = (size_t)(n0 + lr) * DMODEL + k0 + lc;
            *(uint4*)(&Ash[lr][lc])     = *(const uint4*)(xh + aoff);
            *(uint4*)(&Ash[lr][lc + 8]) = *(const uint4*)(xh + aoff + 8);
            *(uint4*)(&Bsh[lr][lc])     = *(const uint4*)(Bh + boff);
            *(uint4*)(&Bsh[lr][lc + 8]) = *(const uint4*)(Bh + boff + 8);
            __syncthreads();

            #pragma unroll
            for (int hk = 0; hk < 2; hk++) {
                const int kc0 = hk * 32 + quad * 8;
                short8 a0 = *(const short8*)(&Ash[wm + fr][kc0]);
                short8 a1 = *(const short8*)(&Ash[wm + 16 + fr][kc0]);
                short8 b0 = *(const short8*)(&Bsh[wn + fr][kc0]);
                short8 b1 = *(const short8*)(&Bsh[wn + 16 + fr][kc0]);
                acc[0][0] = __builtin_amdgcn_mfma_f32_16x16x32_bf16(a0, b0, acc[0][0], 0, 0, 0);
                acc[0][1] = __builtin_amdgcn_mfma_f32_16x16x32_bf16(a0, b1, acc[0][1], 0, 0, 0);
                acc[1][0] = __builtin_amdgcn_mfma_f32_16x16x32_bf16(a1, b0, acc[1][0], 0, 0, 0);
                acc[1][1] = __builtin_amdgcn_mfma_f32_16x16x32_bf16(a1, b1, acc[1][1], 0, 0, 0);
            }
            __syncthreads();
        }

        if (widx == 0) {
            #pragma unroll
            for (int tm = 0; tm < 2; tm++)
            #pragma unroll
            for (int tn = 0; tn < 2; tn++)
            #pragma unroll
            for (int r = 0; r < 4; r++) {
                int row = m0 + wm + tm * 16 + quad * 4 + r;
                int col = n0 + wn + tn * 16 + fr;
                Q[(size_t)row * DMODEL + col] = acc[tm][tn][r];
            }
        } else if (widx == 1) {
            #pragma unroll
            for (int tm = 0; tm < 2; tm++)
            #pragma unroll
            for (int tn = 0; tn < 2; tn++)
            #pragma unroll
            for (int r = 0; r < 4; r++) {
                float v = acc[tm][tn][r];
                float nb = __shfl_xor(v, 1);
                if (!(fr & 1)) {
                    int f = n0 + wn + tn * 16 + fr;
                    int n = m0 + wm + tm * 16 + quad * 4 + r;
                    unsigned p = (unsigned)bf16bits(v) | ((unsigned)bf16bits(nb) << 16);
                    Ktp[(size_t)(f >> 1) * NTOK + n] = p;
                }
            }
        } else {
            #pragma unroll
            for (int tm = 0; tm < 2; tm++)
            #pragma unroll
            for (int tn = 0; tn < 2; tn++)
            #pragma unroll
            for (int rp = 0; rp < 2; rp++) {
                int row = m0 + wm + tm * 16 + quad * 4 + 2 * rp;
                int col = n0 + wn + tn * 16 + fr;
                unsigned p = (unsigned)bf16bits(acc[tm][tn][2 * rp]) |
                             ((unsigned)bf16bits(acc[tm][tn][2 * rp + 1]) << 16);
                Vp[(size_t)(row >> 1) * DMODEL + col] = p;
            }
        }
    }
}

// ---------------------------------------------------------------------------
// E: FUSED attention: one wave per (n,h). inter (2 blocks) + causal intra +
// gated blend. Packed bf16 pairs + dot2; readlane broadcasts. Writes oh bf16.
// ---------------------------------------------------------------------------
__global__ __launch_bounds__(256) void attn_fused_kernel(
    const float* __restrict__ Q, const unsigned* __restrict__ Ktp,
    const unsigned* __restrict__ Vp, const int2* __restrict__ idx_t,
    const float2* __restrict__ gate, __hip_bfloat16* __restrict__ oh)
{
    const int wave = threadIdx.x >> 6, lane = threadIdx.x & 63;
    const int gw = blockIdx.x * 4 + wave;   // = n*16 + h
    const int n = gw >> 4, h = gw & 15;
    const int qi = n & 63;
    const int rown = (n >> 6) * CHUNK;
    const int2 sel = idx_t[(h << 10) | n];
    const int r1 = sel.x * CHUNK, r2 = sel.y * CHUNK;

    const float qreg = Q[(size_t)n * DMODEL + h * HDIM + lane];
    const unsigned qpack = packpair(qreg);            // valid at even lanes
    const unsigned* Ktph = Ktp + (size_t)h * 32 * NTOK;

    float s0 = 0.f, s1 = 0.f, si = 0.f;
    #pragma unroll 8
    for (int d2 = 0; d2 < 32; d2++) {
        const unsigned qp = rlu(qpack, 2 * d2);
        const unsigned* row = Ktph + (size_t)d2 * NTOK;
        s0 = dot2bf(row[r1 + lane], qp, s0);
        s1 = dot2bf(row[r2 + lane], qp, s1);
        si = dot2bf(row[rown + lane], qp, si);
    }
    s0 *= 0.125f; s1 *= 0.125f; si *= 0.125f;

    float m = fmaxf(s0, s1);
    #pragma unroll
    for (int off = 32; off; off >>= 1) m = fmaxf(m, __shfl_xor(m, off));
    const float e0 = expf(s0 - m), e1 = expf(s1 - m);
    float sum = e0 + e1;
    #pragma unroll
    for (int off = 32; off; off >>= 1) sum += __shfl_xor(sum, off);

    float sim = (lane > qi) ? -INFINITY : si;
    float mi = sim;
    #pragma unroll
    for (int off = 32; off; off >>= 1) mi = fmaxf(mi, __shfl_xor(mi, off));
    const float ei = (lane > qi) ? 0.f : expf(si - mi);
    float sumi = ei;
    #pragma unroll
    for (int off = 32; off; off >>= 1) sumi += __shfl_xor(sumi, off);

    const unsigned e0p = packpair(e0);
    const unsigned e1p = packpair(e1);
    const unsigned eip = packpair(ei);

    const unsigned* Vph = Vp + h * HDIM + lane;
    float oa = 0.f, ob = 0.f, oi = 0.f;
    const int b1k = r1 >> 1, b2k = r2 >> 1, bik = rown >> 1;
    #pragma unroll 8
    for (int k2 = 0; k2 < 32; k2++) {
        oa = dot2bf(Vph[(size_t)(b1k + k2) * DMODEL], rlu(e0p, 2 * k2), oa);
        ob = dot2bf(Vph[(size_t)(b2k + k2) * DMODEL], rlu(e1p, 2 * k2), ob);
    }
    const int k2max = qi >> 1;                        // wave-uniform
    #pragma unroll 4
    for (int k2 = 0; k2 <= k2max; k2++) {
        oi = dot2bf(Vph[(size_t)(bik + k2) * DMODEL], rlu(eip, 2 * k2), oi);
    }

    const float2 gt = gate[gw];
    const float val = gt.x * ((oa + ob) / sum) + gt.y * (oi / sumi);
    oh[(size_t)n * DMODEL + h * HDIM + lane] = __float2bfloat16(val);
}

// ---------------------------------------------------------------------------
// F: Wo GEMM: C = oh x (Woh + Wol)^T, 64x64 tile, BK=64, f32 store.
// ---------------------------------------------------------------------------
__global__ __launch_bounds__(256) void gemm_wo(
    const __hip_bfloat16* __restrict__ Ah,
    const __hip_bfloat16* __restrict__ Bh, const __hip_bfloat16* __restrict__ Bl,
    float* __restrict__ C)
{
    __shared__ alignas(16) __hip_bfloat16 Ash[64][72];
    __shared__ alignas(16) __hip_bfloat16 Bsh[64][72];
    __shared__ alignas(16) __hip_bfloat16 Bsl[64][72];

    const int n0 = blockIdx.x * 64;
    const int m0 = blockIdx.y * 64;

    const int tid  = threadIdx.x;
    const int wave = tid >> 6;
    const int lane = tid & 63;
    const int lr = tid >> 2;
    const int lc = (tid & 3) * 16;
    const int wm = (wave >> 1) * 32;
    const int wn = (wave & 1) * 32;
    const int fr = lane & 15;
    const int quad = lane >> 4;

    f32x4 acc[2][2] = {};

    for (int k0 = 0; k0 < DMODEL; k0 += 64) {
        const size_t aoff = (size_t)(m0 + lr) * DMODEL + k0 + lc;
        const size_t boff = (size_t)(n0 + lr) * DMODEL + k0 + lc;
        *(uint4*)(&Ash[lr][lc])     = *(const uint4*)(Ah + aoff);
        *(uint4*)(&Ash[lr][lc + 8]) = *(const uint4*)(Ah + aoff + 8);
        *(uint4*)(&Bsh[lr][lc])     = *(const uint4*)(Bh + boff);
        *(uint4*)(&Bsh[lr][lc + 8]) = *(const uint4*)(Bh + boff + 8);
        *(uint4*)(&Bsl[lr][lc])     = *(const uint4*)(Bl + boff);
        *(uint4*)(&Bsl[lr][lc + 8]) = *(const uint4*)(Bl + boff + 8);
        __syncthreads();

        #pragma unroll
        for (int hk = 0; hk < 2; hk++) {
            const int kc0 = hk * 32 + quad * 8;
            short8 a0 = *(const short8*)(&Ash[wm + fr][kc0]);
            short8 a1 = *(const short8*)(&Ash[wm + 16 + fr][kc0]);
            short8 b0h = *(const short8*)(&Bsh[wn + fr][kc0]);
            short8 b1h = *(const short8*)(&Bsh[wn + 16 + fr][kc0]);
            short8 b0l = *(const short8*)(&Bsl[wn + fr][kc0]);
            short8 b1l = *(const short8*)(&Bsl[wn + 16 + fr][kc0]);
            acc[0][0] = __builtin_amdgcn_mfma_f32_16x16x32_bf16(a0, b0l, acc[0][0], 0, 0, 0);
            acc[0][1] = __builtin_amdgcn_mfma_f32_16x16x32_bf16(a0, b1l, acc[0][1], 0, 0, 0);
            acc[1][0] = __builtin_amdgcn_mfma_f32_16x16x32_bf16(a1, b0l, acc[1][0], 0, 0, 0);
            acc[1][1] = __builtin_amdgcn_mfma_f32_16x16x32_bf16(a1, b1l, acc[1][1], 0, 0, 0);
            acc[0][0] = __builtin_amdgcn_mfma_f32_16x16x32_bf16(a0, b0h, acc[0][0], 0, 0, 0);
            acc[0][1] = __builtin_amdgcn_mfma_f32_16x16x32_bf16(a0, b1h, acc[0][1], 0, 0, 0);
            acc[1][0] = __builtin_amdgcn_mfma_f32_16x16x32_bf16(a1, b0h, acc[1][0], 0, 0, 0);
            acc[1][1] = __builtin_amdgcn_mfma_f32_16x16x32_bf16(a1, b1h, acc[1][1], 0, 0, 0);
        }
        __syncthreads();
    }

    #pragma unroll
    for (int tm = 0; tm < 2; tm++)
    #pragma unroll
    for (int tn = 0; tn < 2; tn++)
    #pragma unroll
    for (int r = 0; r < 4; r++) {
        int row = m0 + wm + tm * 16 + quad * 4 + r;
        int col = n0 + wn + tn * 16 + fr;
        C[(size_t)row * DMODEL + col] = acc[tm][tn][r];
    }
}

// ---------------------------------------------------------------------------
extern "C" void kernel_launch(void* const* d_in, const int* in_sizes, int n_in,
                              void* d_out, int out_size, void* d_ws, size_t ws_size,
                              hipStream_t stream)
{
    const float* x  = (const float*)d_in[0];
    const float* Wq = (const float*)d_in[1];
    const float* Wk = (const float*)d_in[2];
    const float* Wv = (const float*)d_in[3];
    const float* Wg = (const float*)d_in[4];
    const float* Wo = (const float*)d_in[5];

    const size_t M1 = (size_t)NTOK * DMODEL;   // 1M elems

    // workspace layout (~23.5 MB)
    float* Q       = (float*)d_ws;                    // 4 MB
    unsigned* Ktp  = (unsigned*)(Q + M1);             // 2 MB
    unsigned* Vp   = Ktp + (M1 >> 1);                 // 2 MB
    float* Ut      = (float*)(Vp + (M1 >> 1));        // 1 MB
    float* xm      = Ut + (size_t)DMODEL * 256;       // 64 KB
    float* kc      = xm + NBLK * DMODEL;              // 64 KB
    float2* gate   = (float2*)(kc + NBLK * DMODEL);   // 128 KB
    int2* idx_t    = (int2*)(gate + NTOK * NHEAD);    // 128 KB
    __hip_bfloat16* xh  = (__hip_bfloat16*)(idx_t + NTOK * NHEAD);  // 2 MB
    __hip_bfloat16* Wqh = xh + M1;     // 2 MB
    __hip_bfloat16* Wkh = Wqh + M1;    // 2 MB
    __hip_bfloat16* Wvh = Wkh + M1;    // 2 MB
    __hip_bfloat16* Woh = Wvh + M1;    // 2 MB
    __hip_bfloat16* Wol = Woh + M1;    // 2 MB
    __hip_bfloat16* oh  = Wol + M1;    // 2 MB

    prep_kernel<<<6208, 256, 0, stream>>>(
        x, Wq, Wk, Wv, Wo, Wg, xh, Wqh, Wkh, Wvh, Woh, Wol, xm, gate);

    kc_gemm_kernel<<<1024, 256, 0, stream>>>(xm, Wk, kc);
    u_kernel<<<256, 256, 0, stream>>>(kc, Wq, Ut);

    qkv_score_kernel<<<1792, 256, 0, stream>>>(
        xh, Wqh, Wkh, Wvh, x, Ut, Q, Ktp, Vp, idx_t);

    attn_fused_kernel<<<NTOK * NHEAD / 4, 256, 0, stream>>>(Q, Ktp, Vp, idx_t, gate, oh);

    dim3 gwo(16, 16);
    gemm_wo<<<gwo, 256, 0, stream>>>(oh, Woh, Wol, (float*)d_out);
}

// Round 17
// 193.451 us; speedup vs baseline: 1.1199x; 1.0963x over previous
//
#include <hip/hip_runtime.h>
#include <hip/hip_bf16.h>
#include <math.h>

// Problem: B=1, N=1024, D=1024, H=16, C=64, TOPK=2, HD=64, G=16
// Inputs (float32): x, Wq, Wk, Wv [1024x1024], Wg[32,1024], Wo[1024,1024]
// Output (float32): [1024,1024]
//
// Selection: kc = (chunk-mean x) @ Wk^T (exact f32); U[h,g] = Wq_h^T kc
// (exact f32, then split hi/lo bf16); S = x @ U^T via bf16x2 split MFMA
// (rel err ~1e-5 — flip-free class, rounds 4-12). Top-2 inline in attn.
// Q/K/V proj plain bf16 MFMA; K/V epilogues emit packed bf16 pairs.
// Wo GEMM: oh x (Woh + Wol). Attention: wave per (n,h), dot2 pairs, readlane.

typedef __attribute__((ext_vector_type(8))) short short8;   // 8 bf16 = 4 VGPRs
typedef __attribute__((ext_vector_type(4))) float f32x4;
typedef __attribute__((ext_vector_type(2))) __bf16 bf16x2v;

#define NTOK 1024
#define DMODEL 1024
#define NHEAD 16
#define HDIM 64
#define CHUNK 64
#define NBLK 16

__device__ __forceinline__ unsigned rlu(unsigned v, int l)
{
    return (unsigned)__builtin_amdgcn_readlane((int)v, l);
}

__device__ __forceinline__ unsigned short bf16bits(float v)
{
    __hip_bfloat16 h = __float2bfloat16(v);
    return __builtin_bit_cast(unsigned short, h);
}

__device__ __forceinline__ float dot2bf(unsigned a, unsigned b, float acc)
{
#if __has_builtin(__builtin_amdgcn_fdot2_f32_bf16)
    return __builtin_amdgcn_fdot2_f32_bf16(
        __builtin_bit_cast(bf16x2v, a), __builtin_bit_cast(bf16x2v, b), acc, false);
#else
    float a0 = __uint_as_float(a << 16), a1 = __uint_as_float(a & 0xffff0000u);
    float b0 = __uint_as_float(b << 16), b1 = __uint_as_float(b & 0xffff0000u);
    return acc + a0 * b0 + a1 * b1;
#endif
}

// pack (own, lane^1) bf16 bits into a uint; valid at EVEN lanes (own=low)
__device__ __forceinline__ unsigned packpair(float v)
{
    unsigned b = bf16bits(v);
    unsigned nb = (unsigned)__shfl_xor((int)b, 1) & 0xffffu;
    return b | (nb << 16);
}

// ---------------------------------------------------------------------------
// A: prep. blockIdx roles: [0,5120) casts (which = bid>>10: 0 x split,
// 1 Wq hi, 2 Wk hi, 3 Wv hi, 4 Wo split), [5120,5184) xm, [5184,6208) gate.
// ---------------------------------------------------------------------------
__global__ __launch_bounds__(256) void prep_kernel(
    const float* __restrict__ x,  const float* __restrict__ Wq,
    const float* __restrict__ Wk, const float* __restrict__ Wv,
    const float* __restrict__ Wo, const float* __restrict__ Wg,
    __hip_bfloat16* __restrict__ xh,  __hip_bfloat16* __restrict__ xl,
    __hip_bfloat16* __restrict__ Wqh,
    __hip_bfloat16* __restrict__ Wkh, __hip_bfloat16* __restrict__ Wvh,
    __hip_bfloat16* __restrict__ Woh, __hip_bfloat16* __restrict__ Wol,
    float* __restrict__ xm, float2* __restrict__ gate)
{
    __shared__ float gs[32];
    const int bid = blockIdx.x;
    if (bid < 5120) {
        const int which = bid >> 10;
        const int b = bid & 1023;
        const int i = (b * 256 + threadIdx.x) * 4;
        const float* in; __hip_bfloat16 *hi, *lo = nullptr;
        if (which == 0)      { in = x;  hi = xh;  lo = xl; }
        else if (which == 1) { in = Wq; hi = Wqh; }
        else if (which == 2) { in = Wk; hi = Wkh; }
        else if (which == 3) { in = Wv; hi = Wvh; }
        else                 { in = Wo; hi = Woh; lo = Wol; }
        float4 v = *(const float4*)(in + i);
        float vv[4] = {v.x, v.y, v.z, v.w};
        __hip_bfloat16 h[4], l[4];
        #pragma unroll
        for (int j = 0; j < 4; j++) {
            h[j] = __float2bfloat16(vv[j]);
            l[j] = __float2bfloat16(vv[j] - __bfloat162float(h[j]));
        }
        *(uint2*)(hi + i) = *(uint2*)h;
        if (lo) *(uint2*)(lo + i) = *(uint2*)l;
    } else if (bid < 5184) {
        const int b = bid - 5120;
        const int g = b >> 2;
        const int f = (b & 3) * 256 + threadIdx.x;
        float s = 0.f;
        #pragma unroll 8
        for (int c = 0; c < CHUNK; c++) s += x[(size_t)(g * CHUNK + c) * DMODEL + f];
        xm[g * DMODEL + f] = s * (1.0f / CHUNK);
    } else {
        const int n = bid - 5184;
        const int wave = threadIdx.x >> 6, lane = threadIdx.x & 63;
        #pragma unroll
        for (int jj = 0; jj < 8; jj++) {
            int j = wave * 8 + jj;
            float s = 0.f;
            #pragma unroll
            for (int t = 0; t < 16; t++) {
                int d = lane + (t << 6);
                s += x[n * DMODEL + d] * Wg[j * DMODEL + d];
            }
            #pragma unroll
            for (int off = 32; off; off >>= 1) s += __shfl_xor(s, off);
            if (lane == 0) gs[j] = s;
        }
        __syncthreads();
        if (threadIdx.x < NHEAD) {
            int h = threadIdx.x;
            float a = gs[2 * h], b = gs[2 * h + 1];
            float m = fmaxf(a, b);
            float ea = expf(a - m), eb = expf(b - m);
            float inv = 1.f / (ea + eb);
            gate[n * NHEAD + h] = make_float2(ea * inv, eb * inv);
        }
    }
}

// ---------------------------------------------------------------------------
// B: kc = xm @ Wk^T (exact f32). One block per f; (g = tid>>4, sub = tid&15).
// ---------------------------------------------------------------------------
__global__ __launch_bounds__(256) void kc_gemm_kernel(
    const float* __restrict__ xm, const float* __restrict__ Wk,
    float* __restrict__ kc)
{
    const int f = blockIdx.x;
    const int g = threadIdx.x >> 4;
    const int sub = threadIdx.x & 15;
    const float* wrow = Wk + (size_t)f * DMODEL;
    float s = 0.f;
    #pragma unroll 16
    for (int i = 0; i < 64; i++) {
        int e = i * 16 + sub;
        s += xm[g * DMODEL + e] * wrow[e];
    }
    #pragma unroll
    for (int off = 8; off; off >>= 1) s += __shfl_xor(s, off);
    if (sub == 0) kc[g * DMODEL + f] = s;
}

// ---------------------------------------------------------------------------
// C: U[(h<<4)|g][f] = sum_d kc[g][h*64+d] * Wq[h*64+d][f]  (exact f32),
// then split to bf16 hi/lo rows Uh/Ul [256][1024].
// ---------------------------------------------------------------------------
__global__ __launch_bounds__(256) void u_kernel(
    const float* __restrict__ kc, const float* __restrict__ Wq,
    __hip_bfloat16* __restrict__ Uh, __hip_bfloat16* __restrict__ Ul)
{
    __shared__ float kcs[64];
    const int h = blockIdx.x >> 4, g = blockIdx.x & 15;
    if (threadIdx.x < 64) kcs[threadIdx.x] = kc[g * DMODEL + h * HDIM + threadIdx.x];
    __syncthreads();
    const int col = (h << 4) | g;
    for (int f = threadIdx.x; f < DMODEL; f += 256) {
        float s = 0.f;
        #pragma unroll 16
        for (int d = 0; d < 64; d++)
            s += kcs[d] * Wq[(size_t)(h * HDIM + d) * DMODEL + f];
        __hip_bfloat16 hv = __float2bfloat16(s);
        Uh[(size_t)col * DMODEL + f] = hv;
        Ul[(size_t)col * DMODEL + f] = __float2bfloat16(s - __bfloat162float(hv));
    }
}

// ---------------------------------------------------------------------------
// D: qkv GEMMs (blocks [0,768), BK=64, plain bf16) + score GEMM (blocks
// [768,832): S[1024][256] = (xh+xl) @ (Uh+Ul)^T, 3-term split, ~1e-5 rel).
// ---------------------------------------------------------------------------
__global__ __launch_bounds__(256) void qkv_score_kernel(
    const __hip_bfloat16* __restrict__ xh, const __hip_bfloat16* __restrict__ xl,
    const __hip_bfloat16* __restrict__ Wqh, const __hip_bfloat16* __restrict__ Wkh,
    const __hip_bfloat16* __restrict__ Wvh,
    const __hip_bfloat16* __restrict__ Uh, const __hip_bfloat16* __restrict__ Ul,
    float* __restrict__ Q, unsigned* __restrict__ Ktp, unsigned* __restrict__ Vp,
    float* __restrict__ S)
{
    __shared__ uint4 smem4[36864 / 16];     // 36 KB shared scratch, 16B-aligned
    char* smem = (char*)smem4;
    const int b = blockIdx.x;

    const int tid  = threadIdx.x;
    const int wave = tid >> 6;
    const int lane = tid & 63;
    const int lr = tid >> 2;
    const int lc = (tid & 3) * 16;
    const int wm = (wave >> 1) * 32;
    const int wn = (wave & 1) * 32;
    const int fr = lane & 15;
    const int quad = lane >> 4;

    if (b < 768) {
        // ---- QKV GEMM (plain bf16) ----
        __hip_bfloat16 (*Ash)[72] = (__hip_bfloat16(*)[72])smem;
        __hip_bfloat16 (*Bsh)[72] = (__hip_bfloat16(*)[72])(smem + 9216);

        const int widx = b >> 8;
        const int t = b & 255;
        const __hip_bfloat16* __restrict__ Bh =
            (widx == 0) ? Wqh : (widx == 1) ? Wkh : Wvh;
        const int n0 = (t & 15) * 64;
        const int m0 = (t >> 4) * 64;

        f32x4 acc[2][2] = {};

        for (int k0 = 0; k0 < DMODEL; k0 += 64) {
            const size_t aoff = (size_t)(m0 + lr) * DMODEL + k0 + lc;
            const size_t boff = (size_t)(n0 + lr) * DMODEL + k0 + lc;
            *(uint4*)(&Ash[lr][lc])     = *(const uint4*)(xh + aoff);
            *(uint4*)(&Ash[lr][lc + 8]) = *(const uint4*)(xh + aoff + 8);
            *(uint4*)(&Bsh[lr][lc])     = *(const uint4*)(Bh + boff);
            *(uint4*)(&Bsh[lr][lc + 8]) = *(const uint4*)(Bh + boff + 8);
            __syncthreads();

            #pragma unroll
            for (int hk = 0; hk < 2; hk++) {
                const int kc0 = hk * 32 + quad * 8;
                short8 a0 = *(const short8*)(&Ash[wm + fr][kc0]);
                short8 a1 = *(const short8*)(&Ash[wm + 16 + fr][kc0]);
                short8 b0 = *(const short8*)(&Bsh[wn + fr][kc0]);
                short8 b1 = *(const short8*)(&Bsh[wn + 16 + fr][kc0]);
                acc[0][0] = __builtin_amdgcn_mfma_f32_16x16x32_bf16(a0, b0, acc[0][0], 0, 0, 0);
                acc[0][1] = __builtin_amdgcn_mfma_f32_16x16x32_bf16(a0, b1, acc[0][1], 0, 0, 0);
                acc[1][0] = __builtin_amdgcn_mfma_f32_16x16x32_bf16(a1, b0, acc[1][0], 0, 0, 0);
                acc[1][1] = __builtin_amdgcn_mfma_f32_16x16x32_bf16(a1, b1, acc[1][1], 0, 0, 0);
            }
            __syncthreads();
        }

        if (widx == 0) {
            #pragma unroll
            for (int tm = 0; tm < 2; tm++)
            #pragma unroll
            for (int tn = 0; tn < 2; tn++)
            #pragma unroll
            for (int r = 0; r < 4; r++) {
                int row = m0 + wm + tm * 16 + quad * 4 + r;
                int col = n0 + wn + tn * 16 + fr;
                Q[(size_t)row * DMODEL + col] = acc[tm][tn][r];
            }
        } else if (widx == 1) {
            #pragma unroll
            for (int tm = 0; tm < 2; tm++)
            #pragma unroll
            for (int tn = 0; tn < 2; tn++)
            #pragma unroll
            for (int r = 0; r < 4; r++) {
                float v = acc[tm][tn][r];
                float nb = __shfl_xor(v, 1);
                if (!(fr & 1)) {
                    int f = n0 + wn + tn * 16 + fr;
                    int n = m0 + wm + tm * 16 + quad * 4 + r;
                    unsigned p = (unsigned)bf16bits(v) | ((unsigned)bf16bits(nb) << 16);
                    Ktp[(size_t)(f >> 1) * NTOK + n] = p;
                }
            }
        } else {
            #pragma unroll
            for (int tm = 0; tm < 2; tm++)
            #pragma unroll
            for (int tn = 0; tn < 2; tn++)
            #pragma unroll
            for (int rp = 0; rp < 2; rp++) {
                int row = m0 + wm + tm * 16 + quad * 4 + 2 * rp;
                int col = n0 + wn + tn * 16 + fr;
                unsigned p = (unsigned)bf16bits(acc[tm][tn][2 * rp]) |
                             ((unsigned)bf16bits(acc[tm][tn][2 * rp + 1]) << 16);
                Vp[(size_t)(row >> 1) * DMODEL + col] = p;
            }
        }
    } else {
        // ---- score GEMM: S = (xh+xl) @ (Uh+Ul)^T, 3-term split ----
        __hip_bfloat16 (*Ash)[72] = (__hip_bfloat16(*)[72])smem;
        __hip_bfloat16 (*Asl)[72] = (__hip_bfloat16(*)[72])(smem + 9216);
        __hip_bfloat16 (*Bsh)[72] = (__hip_bfloat16(*)[72])(smem + 18432);
        __hip_bfloat16 (*Bsl)[72] = (__hip_bfloat16(*)[72])(smem + 27648);

        const int bb = b - 768;                 // [0,64)
        const int m0 = (bb >> 2) * 64;          // 16 token tiles
        const int n0 = (bb & 3) * 64;           // 4 col tiles (256 cols)

        f32x4 acc[2][2] = {};

        for (int k0 = 0; k0 < DMODEL; k0 += 64) {
            const size_t aoff = (size_t)(m0 + lr) * DMODEL + k0 + lc;
            const size_t boff = (size_t)(n0 + lr) * DMODEL + k0 + lc;
            *(uint4*)(&Ash[lr][lc])     = *(const uint4*)(xh + aoff);
            *(uint4*)(&Ash[lr][lc + 8]) = *(const uint4*)(xh + aoff + 8);
            *(uint4*)(&Asl[lr][lc])     = *(const uint4*)(xl + aoff);
            *(uint4*)(&Asl[lr][lc + 8]) = *(const uint4*)(xl + aoff + 8);
            *(uint4*)(&Bsh[lr][lc])     = *(const uint4*)(Uh + boff);
            *(uint4*)(&Bsh[lr][lc + 8]) = *(const uint4*)(Uh + boff + 8);
            *(uint4*)(&Bsl[lr][lc])     = *(const uint4*)(Ul + boff);
            *(uint4*)(&Bsl[lr][lc + 8]) = *(const uint4*)(Ul + boff + 8);
            __syncthreads();

            #pragma unroll
            for (int hk = 0; hk < 2; hk++) {
                const int kc0 = hk * 32 + quad * 8;
                short8 a0h = *(const short8*)(&Ash[wm + fr][kc0]);
                short8 a1h = *(const short8*)(&Ash[wm + 16 + fr][kc0]);
                short8 a0l = *(const short8*)(&Asl[wm + fr][kc0]);
                short8 a1l = *(const short8*)(&Asl[wm + 16 + fr][kc0]);
                short8 b0h = *(const short8*)(&Bsh[wn + fr][kc0]);
                short8 b1h = *(const short8*)(&Bsh[wn + 16 + fr][kc0]);
                short8 b0l = *(const short8*)(&Bsl[wn + fr][kc0]);
                short8 b1l = *(const short8*)(&Bsl[wn + 16 + fr][kc0]);
                acc[0][0] = __builtin_amdgcn_mfma_f32_16x16x32_bf16(a0l, b0h, acc[0][0], 0, 0, 0);
                acc[0][1] = __builtin_amdgcn_mfma_f32_16x16x32_bf16(a0l, b1h, acc[0][1], 0, 0, 0);
                acc[1][0] = __builtin_amdgcn_mfma_f32_16x16x32_bf16(a1l, b0h, acc[1][0], 0, 0, 0);
                acc[1][1] = __builtin_amdgcn_mfma_f32_16x16x32_bf16(a1l, b1h, acc[1][1], 0, 0, 0);
                acc[0][0] = __builtin_amdgcn_mfma_f32_16x16x32_bf16(a0h, b0l, acc[0][0], 0, 0, 0);
                acc[0][1] = __builtin_amdgcn_mfma_f32_16x16x32_bf16(a0h, b1l, acc[0][1], 0, 0, 0);
                acc[1][0] = __builtin_amdgcn_mfma_f32_16x16x32_bf16(a1h, b0l, acc[1][0], 0, 0, 0);
                acc[1][1] = __builtin_amdgcn_mfma_f32_16x16x32_bf16(a1h, b1l, acc[1][1], 0, 0, 0);
                acc[0][0] = __builtin_amdgcn_mfma_f32_16x16x32_bf16(a0h, b0h, acc[0][0], 0, 0, 0);
                acc[0][1] = __builtin_amdgcn_mfma_f32_16x16x32_bf16(a0h, b1h, acc[0][1], 0, 0, 0);
                acc[1][0] = __builtin_amdgcn_mfma_f32_16x16x32_bf16(a1h, b0h, acc[1][0], 0, 0, 0);
                acc[1][1] = __builtin_amdgcn_mfma_f32_16x16x32_bf16(a1h, b1h, acc[1][1], 0, 0, 0);
            }
            __syncthreads();
        }

        #pragma unroll
        for (int tm = 0; tm < 2; tm++)
        #pragma unroll
        for (int tn = 0; tn < 2; tn++)
        #pragma unroll
        for (int r = 0; r < 4; r++) {
            int row = m0 + wm + tm * 16 + quad * 4 + r;
            int col = n0 + wn + tn * 16 + fr;
            S[(size_t)row * 256 + col] = acc[tm][tn][r];
        }
    }
}

// ---------------------------------------------------------------------------
// E: FUSED attention: one wave per (n,h). Inline masked top-2 from S
// (ties -> lowest index; all-masked -> (0,1)), then inter (2 blocks) +
// causal intra + gated blend. Packed bf16 pairs + dot2. Writes oh bf16.
// ---------------------------------------------------------------------------
__global__ __launch_bounds__(256) void attn_fused_kernel(
    const float* __restrict__ Q, const unsigned* __restrict__ Ktp,
    const unsigned* __restrict__ Vp, const float* __restrict__ S,
    const float2* __restrict__ gate, __hip_bfloat16* __restrict__ oh)
{
    const int wave = threadIdx.x >> 6, lane = threadIdx.x & 63;
    const int gw = blockIdx.x * 4 + wave;   // = n*16 + h
    const int n = gw >> 4, h = gw & 15;
    const int qi = n & 63;
    const int rown = (n >> 6) * CHUNK;

    // inline top-2 (all lanes compute identically; loads broadcast)
    const float* Sn = S + (size_t)n * 256 + h * 16;
    int i1 = -1, i2 = -1;
    {
        float s[NBLK];
        #pragma unroll
        for (int g = 0; g < NBLK; g++)
            s[g] = (n >= (g << 6)) ? -INFINITY : Sn[g];
        float b1 = -INFINITY;
        #pragma unroll
        for (int g = 0; g < NBLK; g++) if (i1 < 0 || s[g] > b1) { b1 = s[g]; i1 = g; }
        float b2 = -INFINITY;
        #pragma unroll
        for (int g = 0; g < NBLK; g++) { if (g == i1) continue; if (i2 < 0 || s[g] > b2) { b2 = s[g]; i2 = g; } }
    }
    const int r1 = i1 * CHUNK, r2 = i2 * CHUNK;

    const float qreg = Q[(size_t)n * DMODEL + h * HDIM + lane];
    const unsigned qpack = packpair(qreg);            // valid at even lanes
    const unsigned* Ktph = Ktp + (size_t)h * 32 * NTOK;

    float s0 = 0.f, s1 = 0.f, si = 0.f;
    #pragma unroll 8
    for (int d2 = 0; d2 < 32; d2++) {
        const unsigned qp = rlu(qpack, 2 * d2);
        const unsigned* row = Ktph + (size_t)d2 * NTOK;
        s0 = dot2bf(row[r1 + lane], qp, s0);
        s1 = dot2bf(row[r2 + lane], qp, s1);
        si = dot2bf(row[rown + lane], qp, si);
    }
    s0 *= 0.125f; s1 *= 0.125f; si *= 0.125f;

    float m = fmaxf(s0, s1);
    #pragma unroll
    for (int off = 32; off; off >>= 1) m = fmaxf(m, __shfl_xor(m, off));
    const float e0 = expf(s0 - m), e1 = expf(s1 - m);
    float sum = e0 + e1;
    #pragma unroll
    for (int off = 32; off; off >>= 1) sum += __shfl_xor(sum, off);

    float sim = (lane > qi) ? -INFINITY : si;
    float mi = sim;
    #pragma unroll
    for (int off = 32; off; off >>= 1) mi = fmaxf(mi, __shfl_xor(mi, off));
    const float ei = (lane > qi) ? 0.f : expf(si - mi);
    float sumi = ei;
    #pragma unroll
    for (int off = 32; off; off >>= 1) sumi += __shfl_xor(sumi, off);

    const unsigned e0p = packpair(e0);
    const unsigned e1p = packpair(e1);
    const unsigned eip = packpair(ei);

    const unsigned* Vph = Vp + h * HDIM + lane;
    float oa = 0.f, ob = 0.f, oi = 0.f;
    const int b1k = r1 >> 1, b2k = r2 >> 1, bik = rown >> 1;
    #pragma unroll 8
    for (int k2 = 0; k2 < 32; k2++) {
        oa = dot2bf(Vph[(size_t)(b1k + k2) * DMODEL], rlu(e0p, 2 * k2), oa);
        ob = dot2bf(Vph[(size_t)(b2k + k2) * DMODEL], rlu(e1p, 2 * k2), ob);
    }
    const int k2max = qi >> 1;                        // wave-uniform
    #pragma unroll 4
    for (int k2 = 0; k2 <= k2max; k2++) {
        oi = dot2bf(Vph[(size_t)(bik + k2) * DMODEL], rlu(eip, 2 * k2), oi);
    }

    const float2 gt = gate[gw];
    const float val = gt.x * ((oa + ob) / sum) + gt.y * (oi / sumi);
    oh[(size_t)n * DMODEL + h * HDIM + lane] = __float2bfloat16(val);
}

// ---------------------------------------------------------------------------
// F: Wo GEMM: C = oh x (Woh + Wol)^T, 64x64 tile, BK=64, f32 store.
// ---------------------------------------------------------------------------
__global__ __launch_bounds__(256) void gemm_wo(
    const __hip_bfloat16* __restrict__ Ah,
    const __hip_bfloat16* __restrict__ Bh, const __hip_bfloat16* __restrict__ Bl,
    float* __restrict__ C)
{
    __shared__ alignas(16) __hip_bfloat16 Ash[64][72];
    __shared__ alignas(16) __hip_bfloat16 Bsh[64][72];
    __shared__ alignas(16) __hip_bfloat16 Bsl[64][72];

    const int n0 = blockIdx.x * 64;
    const int m0 = blockIdx.y * 64;

    const int tid  = threadIdx.x;
    const int wave = tid >> 6;
    const int lane = tid & 63;
    const int lr = tid >> 2;
    const int lc = (tid & 3) * 16;
    const int wm = (wave >> 1) * 32;
    const int wn = (wave & 1) * 32;
    const int fr = lane & 15;
    const int quad = lane >> 4;

    f32x4 acc[2][2] = {};

    for (int k0 = 0; k0 < DMODEL; k0 += 64) {
        const size_t aoff = (size_t)(m0 + lr) * DMODEL + k0 + lc;
        const size_t boff = (size_t)(n0 + lr) * DMODEL + k0 + lc;
        *(uint4*)(&Ash[lr][lc])     = *(const uint4*)(Ah + aoff);
        *(uint4*)(&Ash[lr][lc + 8]) = *(const uint4*)(Ah + aoff + 8);
        *(uint4*)(&Bsh[lr][lc])     = *(const uint4*)(Bh + boff);
        *(uint4*)(&Bsh[lr][lc + 8]) = *(const uint4*)(Bh + boff + 8);
        *(uint4*)(&Bsl[lr][lc])     = *(const uint4*)(Bl + boff);
        *(uint4*)(&Bsl[lr][lc + 8]) = *(const uint4*)(Bl + boff + 8);
        __syncthreads();

        #pragma unroll
        for (int hk = 0; hk < 2; hk++) {
            const int kc0 = hk * 32 + quad * 8;
            short8 a0 = *(const short8*)(&Ash[wm + fr][kc0]);
            short8 a1 = *(const short8*)(&Ash[wm + 16 + fr][kc0]);
            short8 b0h = *(const short8*)(&Bsh[wn + fr][kc0]);
            short8 b1h = *(const short8*)(&Bsh[wn + 16 + fr][kc0]);
            short8 b0l = *(const short8*)(&Bsl[wn + fr][kc0]);
            short8 b1l = *(const short8*)(&Bsl[wn + 16 + fr][kc0]);
            acc[0][0] = __builtin_amdgcn_mfma_f32_16x16x32_bf16(a0, b0l, acc[0][0], 0, 0, 0);
            acc[0][1] = __builtin_amdgcn_mfma_f32_16x16x32_bf16(a0, b1l, acc[0][1], 0, 0, 0);
            acc[1][0] = __builtin_amdgcn_mfma_f32_16x16x32_bf16(a1, b0l, acc[1][0], 0, 0, 0);
            acc[1][1] = __builtin_amdgcn_mfma_f32_16x16x32_bf16(a1, b1l, acc[1][1], 0, 0, 0);
            acc[0][0] = __builtin_amdgcn_mfma_f32_16x16x32_bf16(a0, b0h, acc[0][0], 0, 0, 0);
            acc[0][1] = __builtin_amdgcn_mfma_f32_16x16x32_bf16(a0, b1h, acc[0][1], 0, 0, 0);
            acc[1][0] = __builtin_amdgcn_mfma_f32_16x16x32_bf16(a1, b0h, acc[1][0], 0, 0, 0);
            acc[1][1] = __builtin_amdgcn_mfma_f32_16x16x32_bf16(a1, b1h, acc[1][1], 0, 0, 0);
        }
        __syncthreads();
    }

    #pragma unroll
    for (int tm = 0; tm < 2; tm++)
    #pragma unroll
    for (int tn = 0; tn < 2; tn++)
    #pragma unroll
    for (int r = 0; r < 4; r++) {
        int row = m0 + wm + tm * 16 + quad * 4 + r;
        int col = n0 + wn + tn * 16 + fr;
        C[(size_t)row * DMODEL + col] = acc[tm][tn][r];
    }
}

// ---------------------------------------------------------------------------
extern "C" void kernel_launch(void* const* d_in, const int* in_sizes, int n_in,
                              void* d_out, int out_size, void* d_ws, size_t ws_size,
                              hipStream_t stream)
{
    const float* x  = (const float*)d_in[0];
    const float* Wq = (const float*)d_in[1];
    const float* Wk = (const float*)d_in[2];
    const float* Wv = (const float*)d_in[3];
    const float* Wg = (const float*)d_in[4];
    const float* Wo = (const float*)d_in[5];

    const size_t M1 = (size_t)NTOK * DMODEL;   // 1M elems

    // workspace layout (~27 MB)
    float* Q       = (float*)d_ws;                    // 4 MB
    unsigned* Ktp  = (unsigned*)(Q + M1);             // 2 MB
    unsigned* Vp   = Ktp + (M1 >> 1);                 // 2 MB
    float* S       = (float*)(Vp + (M1 >> 1));        // 1 MB  (scores [1024][256])
    float* xm      = S + (size_t)NTOK * 256;          // 64 KB
    float* kc      = xm + NBLK * DMODEL;              // 64 KB
    float2* gate   = (float2*)(kc + NBLK * DMODEL);   // 128 KB
    __hip_bfloat16* xh  = (__hip_bfloat16*)(gate + NTOK * NHEAD);   // 2 MB
    __hip_bfloat16* xl  = xh + M1;     // 2 MB
    __hip_bfloat16* Wqh = xl + M1;     // 2 MB
    __hip_bfloat16* Wkh = Wqh + M1;    // 2 MB
    __hip_bfloat16* Wvh = Wkh + M1;    // 2 MB
    __hip_bfloat16* Woh = Wvh + M1;    // 2 MB
    __hip_bfloat16* Wol = Woh + M1;    // 2 MB
    __hip_bfloat16* oh  = Wol + M1;    // 2 MB
    __hip_bfloat16* Uh  = oh + M1;     // 512 KB ([256][1024])
    __hip_bfloat16* Ul  = Uh + 256 * DMODEL;  // 512 KB

    prep_kernel<<<6208, 256, 0, stream>>>(
        x, Wq, Wk, Wv, Wo, Wg, xh, xl, Wqh, Wkh, Wvh, Woh, Wol, xm, gate);

    kc_gemm_kernel<<<1024, 256, 0, stream>>>(xm, Wk, kc);
    u_kernel<<<256, 256, 0, stream>>>(kc, Wq, Uh, Ul);

    qkv_score_kernel<<<832, 256, 0, stream>>>(
        xh, xl, Wqh, Wkh, Wvh, Uh, Ul, Q, Ktp, Vp, S);

    attn_fused_kernel<<<NTOK * NHEAD / 4, 256, 0, stream>>>(Q, Ktp, Vp, S, gate, oh);

    dim3 gwo(16, 16);
    gemm_wo<<<gwo, 256, 0, stream>>>(oh, Woh, Wol, (float*)d_out);
}